// Round 1
// baseline (2017.969 us; speedup 1.0000x reference)
//
#include <hip/hip_runtime.h>

#define NN 100000
#define NE 640000

// ---------------------------------------------------------------------------
// Lane-per-edge GEMM helpers: weights are wave-uniform (s_load), activations
// per-lane (float4 loads of the lane's own row). acc[] fully static-indexed.
// ---------------------------------------------------------------------------
template<bool RELU>
__device__ __forceinline__ void gemm_region64(const float4* __restrict__ p,
                                              const float* __restrict__ wbase,
                                              float (&acc)[64])
{
    #pragma unroll 1
    for (int kb = 0; kb < 16; ++kb) {
        float4 c = p[kb];
        if (RELU) {
            c.x = fmaxf(c.x, 0.f); c.y = fmaxf(c.y, 0.f);
            c.z = fmaxf(c.z, 0.f); c.w = fmaxf(c.w, 0.f);
        }
        const float* wr = wbase + kb * 4 * 64;
        #pragma unroll
        for (int j = 0; j < 64; ++j) acc[j] = fmaf(c.x, wr[j],       acc[j]);
        #pragma unroll
        for (int j = 0; j < 64; ++j) acc[j] = fmaf(c.y, wr[64 + j],  acc[j]);
        #pragma unroll
        for (int j = 0; j < 64; ++j) acc[j] = fmaf(c.z, wr[128 + j], acc[j]);
        #pragma unroll
        for (int j = 0; j < 64; ++j) acc[j] = fmaf(c.w, wr[192 + j], acc[j]);
    }
}

template<bool RELU>
__device__ __forceinline__ void gemm_region50(const float4* __restrict__ p,
                                              const float* __restrict__ wbase,
                                              float (&acc)[50])
{
    #pragma unroll 1
    for (int kb = 0; kb < 16; ++kb) {
        float4 c = p[kb];
        if (RELU) {
            c.x = fmaxf(c.x, 0.f); c.y = fmaxf(c.y, 0.f);
            c.z = fmaxf(c.z, 0.f); c.w = fmaxf(c.w, 0.f);
        }
        const float* wr = wbase + kb * 4 * 50;
        #pragma unroll
        for (int j = 0; j < 50; ++j) acc[j] = fmaf(c.x, wr[j],       acc[j]);
        #pragma unroll
        for (int j = 0; j < 50; ++j) acc[j] = fmaf(c.y, wr[50 + j],  acc[j]);
        #pragma unroll
        for (int j = 0; j < 50; ++j) acc[j] = fmaf(c.z, wr[100 + j], acc[j]);
        #pragma unroll
        for (int j = 0; j < 50; ++j) acc[j] = fmaf(c.w, wr[150 + j], acc[j]);
    }
}

// ---------------------------------------------------------------------------
// x = x_in @ node_emb_w[32,64] + b   (thread per output element)
// ---------------------------------------------------------------------------
__global__ __launch_bounds__(256) void k_node_emb(const float* __restrict__ xin,
                                                  const float* __restrict__ w,
                                                  const float* __restrict__ b,
                                                  float* __restrict__ xout)
{
    int idx = blockIdx.x * 256 + threadIdx.x;   // NN*64 threads
    int n = idx >> 6, j = idx & 63;
    const float* xr = xin + (size_t)n * 32;
    float t = b[j];
    #pragma unroll
    for (int k = 0; k < 32; ++k) t = fmaf(xr[k], w[k * 64 + j], t);
    xout[idx] = t;
}

// ---------------------------------------------------------------------------
// e = edge_attr @ edge_emb_w[16,64] + b
// ---------------------------------------------------------------------------
__global__ __launch_bounds__(256) void k_edge_emb(const float* __restrict__ ein,
                                                  const float* __restrict__ w,
                                                  const float* __restrict__ b,
                                                  float* __restrict__ eout)
{
    int idx = blockIdx.x * 256 + threadIdx.x;   // NE*64 threads
    int eid = idx >> 6, j = idx & 63;
    const float* er = ein + (size_t)eid * 16;
    float t = b[j];
    #pragma unroll
    for (int k = 0; k < 16; ++k) t = fmaf(er[k], w[k * 64 + j], t);
    eout[idx] = t;
}

// ---------------------------------------------------------------------------
// msg = relu(x[src] + e @ lw + lb); agg[dst] += msg   (wave per edge, lane=ch)
// ---------------------------------------------------------------------------
__global__ __launch_bounds__(256) void k_msg(const float* __restrict__ x,
                                             const float* __restrict__ e,
                                             const int* __restrict__ src,
                                             const int* __restrict__ dst,
                                             const float* __restrict__ lw,
                                             const float* __restrict__ lb,
                                             float* __restrict__ agg)
{
    __shared__ float wlds[64 * 64];
    __shared__ float ebuf[4][64];
    int tid = threadIdx.x;
    int w = tid >> 6, j = tid & 63;
    for (int i = tid; i < 64 * 64; i += 256) wlds[i] = lw[i];
    float bj = lb[j];
    __syncthreads();
    for (int base = blockIdx.x * 4; base < NE; base += gridDim.x * 4) {
        int edge = base + w;   // NE % 4 == 0 -> always valid
        ebuf[w][j] = e[(size_t)edge * 64 + j];
        __syncthreads();
        float t = bj;
        #pragma unroll 8
        for (int k = 0; k < 64; ++k) t = fmaf(ebuf[w][k], wlds[k * 64 + j], t);
        int s = src[edge], d = dst[edge];
        float m = fmaxf(x[(size_t)s * 64 + j] + t, 0.f);
        unsafeAtomicAdd(&agg[(size_t)d * 64 + j], m);
        __syncthreads();
    }
}

// ---------------------------------------------------------------------------
// h = relu((x+agg)@w1+b1)@w2+b2 (in place over agg buffer), + BN partial sums
// ---------------------------------------------------------------------------
__global__ __launch_bounds__(256) void k_conv(const float* __restrict__ x,
                                              float* __restrict__ hio,
                                              const float* __restrict__ w1g,
                                              const float* __restrict__ b1,
                                              const float* __restrict__ w2g,
                                              const float* __restrict__ b2,
                                              float* __restrict__ stats)
{
    __shared__ float w1[64 * 64];
    __shared__ float w2[64 * 64];
    __shared__ float buf[4][64];
    __shared__ float red[2][4][64];
    int tid = threadIdx.x, w = tid >> 6, j = tid & 63;
    for (int i = tid; i < 64 * 64; i += 256) { w1[i] = w1g[i]; w2[i] = w2g[i]; }
    float b1j = b1[j], b2j = b2[j];
    __syncthreads();
    float s1 = 0.f, s2 = 0.f;
    for (int base = blockIdx.x * 4; base < NN; base += gridDim.x * 4) {
        int n = base + w;   // NN % 4 == 0 -> always valid
        float hp = x[(size_t)n * 64 + j] + hio[(size_t)n * 64 + j];
        buf[w][j] = hp;
        __syncthreads();
        float h1 = b1j;
        #pragma unroll 8
        for (int k = 0; k < 64; ++k) h1 = fmaf(buf[w][k], w1[k * 64 + j], h1);
        h1 = fmaxf(h1, 0.f);
        __syncthreads();
        buf[w][j] = h1;
        __syncthreads();
        float h2 = b2j;
        #pragma unroll 8
        for (int k = 0; k < 64; ++k) h2 = fmaf(buf[w][k], w2[k * 64 + j], h2);
        hio[(size_t)n * 64 + j] = h2;
        s1 += h2;
        s2 += h2 * h2;
        __syncthreads();
    }
    red[0][w][j] = s1;
    red[1][w][j] = s2;
    __syncthreads();
    if (w == 0) {
        float a = red[0][0][j] + red[0][1][j] + red[0][2][j] + red[0][3][j];
        float c = red[1][0][j] + red[1][1][j] + red[1][2][j] + red[1][3][j];
        unsafeAtomicAdd(&stats[j], a);
        unsafeAtomicAdd(&stats[64 + j], c);
    }
}

// ---------------------------------------------------------------------------
// BN finalize: scale a = gamma*rsqrt(var+eps), shift c = beta - mu*a
// ---------------------------------------------------------------------------
__global__ void k_bnfin(float* __restrict__ stats,
                        const float* __restrict__ gamma,
                        const float* __restrict__ beta)
{
    int j = threadIdx.x;   // 64 threads
    float mu = stats[j] * (1.f / NN);
    float var = stats[64 + j] * (1.f / NN) - mu * mu;
    float a = gamma[j] * rsqrtf(var + 1e-5f);
    stats[128 + j] = a;
    stats[192 + j] = beta[j] - mu * a;
}

// ---------------------------------------------------------------------------
// x = (x + relu(h*a[j] + c[j])) / 2
// ---------------------------------------------------------------------------
__global__ __launch_bounds__(256) void k_xupd(float* __restrict__ x,
                                              const float* __restrict__ h,
                                              const float* __restrict__ stats)
{
    int idx = blockIdx.x * 256 + threadIdx.x;   // NN*64 threads
    int j = idx & 63;
    float r = fmaxf(fmaf(h[idx], stats[128 + j], stats[192 + j]), 0.f);
    x[idx] = (x[idx] + r) * 0.5f;
}

// ---------------------------------------------------------------------------
// e += 0.5 * ( relu(cat(x[src],x[dst],e) @ w1 + b1) @ w2 + b2 )
// lane per edge; acc in VGPRs; weights via wave-uniform scalar loads
// ---------------------------------------------------------------------------
__global__ __launch_bounds__(256) void k_emlp(const float* __restrict__ x,
                                              float* __restrict__ e,
                                              const int* __restrict__ src,
                                              const int* __restrict__ dst,
                                              const float* __restrict__ w1,
                                              const float* __restrict__ b1,
                                              const float* __restrict__ w2,
                                              const float* __restrict__ b2)
{
    int edge = blockIdx.x * 256 + threadIdx.x;   // NE % 256 == 0
    const float4* xs = (const float4*)(x + (size_t)src[edge] * 64);
    const float4* xd = (const float4*)(x + (size_t)dst[edge] * 64);
    float4* er = (float4*)(e + (size_t)edge * 64);

    float acc[64];
    #pragma unroll
    for (int j = 0; j < 64; ++j) acc[j] = b1[j];

    gemm_region64<false>(xs, w1, acc);
    gemm_region64<false>(xd, w1 + 64 * 64, acc);
    gemm_region64<false>((const float4*)er, w1 + 128 * 64, acc);

    #pragma unroll
    for (int j = 0; j < 64; ++j) acc[j] = fmaxf(acc[j], 0.f);

    // second GEMM in 4 column-chunks of 16 to cap register pressure
    #pragma unroll 1
    for (int jc = 0; jc < 4; ++jc) {
        float o[16];
        #pragma unroll
        for (int jj = 0; jj < 16; ++jj) o[jj] = b2[jc * 16 + jj];
        #pragma unroll
        for (int k = 0; k < 64; ++k) {
            #pragma unroll
            for (int jj = 0; jj < 16; ++jj)
                o[jj] = fmaf(acc[k], w2[k * 64 + jc * 16 + jj], o[jj]);
        }
        #pragma unroll
        for (int q = 0; q < 4; ++q) {
            float4 ev = er[jc * 4 + q];
            ev.x = fmaf(0.5f, o[q * 4 + 0], ev.x);
            ev.y = fmaf(0.5f, o[q * 4 + 1], ev.y);
            ev.z = fmaf(0.5f, o[q * 4 + 2], ev.z);
            ev.w = fmaf(0.5f, o[q * 4 + 3], ev.w);
            er[jc * 4 + q] = ev;
        }
    }
}

// ---------------------------------------------------------------------------
// readout: er=[relu(x[src]++x[dst]), e]; logit = relu(relu(er@w1+b1)@w2+b2)@w3+b3
// ---------------------------------------------------------------------------
__global__ __launch_bounds__(256) void k_readout(const float* __restrict__ x,
                                                 const float* __restrict__ e,
                                                 const int* __restrict__ src,
                                                 const int* __restrict__ dst,
                                                 const float* __restrict__ w1,
                                                 const float* __restrict__ b1,
                                                 const float* __restrict__ w2,
                                                 const float* __restrict__ b2,
                                                 const float* __restrict__ w3,
                                                 const float* __restrict__ b3,
                                                 float* __restrict__ logit)
{
    int edge = blockIdx.x * 256 + threadIdx.x;   // NE % 256 == 0
    const float4* xs = (const float4*)(x + (size_t)src[edge] * 64);
    const float4* xd = (const float4*)(x + (size_t)dst[edge] * 64);
    const float4* er = (const float4*)(e + (size_t)edge * 64);

    float a50[50];
    #pragma unroll
    for (int j = 0; j < 50; ++j) a50[j] = b1[j];
    gemm_region50<true>(xs, w1, a50);
    gemm_region50<true>(xd, w1 + 64 * 50, a50);
    gemm_region50<false>(er, w1 + 128 * 50, a50);
    #pragma unroll
    for (int j = 0; j < 50; ++j) a50[j] = fmaxf(a50[j], 0.f);

    float a25[25];
    #pragma unroll
    for (int j = 0; j < 25; ++j) a25[j] = b2[j];
    #pragma unroll
    for (int k = 0; k < 50; ++k) {
        #pragma unroll
        for (int j = 0; j < 25; ++j) a25[j] = fmaf(a50[k], w2[k * 25 + j], a25[j]);
    }

    float lg = b3[0];
    #pragma unroll
    for (int k = 0; k < 25; ++k) lg = fmaf(fmaxf(a25[k], 0.f), w3[k], lg);
    logit[edge] = lg;
}

// ---------------------------------------------------------------------------
extern "C" void kernel_launch(void* const* d_in, const int* in_sizes, int n_in,
                              void* d_out, int out_size, void* d_ws, size_t ws_size,
                              hipStream_t stream)
{
    const float* x_in  = (const float*)d_in[0];
    const float* eattr = (const float*)d_in[1];
    const int*   src   = (const int*)d_in[2];
    const int*   dst   = (const int*)d_in[3];
    const float* n_w   = (const float*)d_in[4];
    const float* n_b   = (const float*)d_in[5];
    const float* e_w   = (const float*)d_in[6];
    const float* e_b   = (const float*)d_in[7];
    const float* lw    = (const float*)d_in[8];
    const float* lb    = (const float*)d_in[9];
    const float* cw1   = (const float*)d_in[10];
    const float* cb1   = (const float*)d_in[11];
    const float* cw2   = (const float*)d_in[12];
    const float* cb2   = (const float*)d_in[13];
    const float* ew1   = (const float*)d_in[14];
    const float* eb1   = (const float*)d_in[15];
    const float* ew2   = (const float*)d_in[16];
    const float* eb2   = (const float*)d_in[17];
    const float* gam   = (const float*)d_in[18];
    const float* bet   = (const float*)d_in[19];
    const float* m1w   = (const float*)d_in[20];
    const float* m1b   = (const float*)d_in[21];
    const float* m2w   = (const float*)d_in[22];
    const float* m2b   = (const float*)d_in[23];
    const float* m3w   = (const float*)d_in[24];
    const float* m3b   = (const float*)d_in[25];

    float* xbuf  = (float*)d_out;                 // [NN,64] -> final x output
    float* logit = xbuf + (size_t)NN * 64;        // [NE]    -> final logits
    float* e_buf = (float*)d_ws;                  // [NE,64]
    float* tmp   = e_buf + (size_t)NE * 64;       // [NN,64] agg -> h (in place)
    float* stats = tmp + (size_t)NN * 64;         // 256 floats

    k_node_emb<<<NN * 64 / 256, 256, 0, stream>>>(x_in, n_w, n_b, xbuf);
    k_edge_emb<<<NE * 64 / 256, 256, 0, stream>>>(eattr, e_w, e_b, e_buf);

    for (int l = 0; l < 2; ++l) {
        hipMemsetAsync(tmp, 0, (size_t)NN * 64 * sizeof(float), stream);
        hipMemsetAsync(stats, 0, 256 * sizeof(float), stream);
        k_msg<<<2048, 256, 0, stream>>>(xbuf, e_buf, src, dst,
                                        lw + l * 64 * 64, lb + l * 64, tmp);
        k_conv<<<2048, 256, 0, stream>>>(xbuf, tmp, cw1 + l * 64 * 64, cb1 + l * 64,
                                         cw2 + l * 64 * 64, cb2 + l * 64, stats);
        k_bnfin<<<1, 64, 0, stream>>>(stats, gam + l * 64, bet + l * 64);
        k_xupd<<<NN * 64 / 256, 256, 0, stream>>>(xbuf, tmp, stats);
        k_emlp<<<NE / 256, 256, 0, stream>>>(xbuf, e_buf, src, dst,
                                             ew1 + l * 192 * 64, eb1 + l * 64,
                                             ew2 + l * 64 * 64, eb2 + l * 64);
    }

    k_readout<<<NE / 256, 256, 0, stream>>>(xbuf, e_buf, src, dst,
                                            m1w, m1b, m2w, m2b, m3w, m3b, logit);
}

// Round 2
// 1168.808 us; speedup vs baseline: 1.7265x; 1.7265x over previous
//
#include <hip/hip_runtime.h>

#define NN 100000
#define NE 640000

typedef __attribute__((ext_vector_type(8))) short short8;
typedef __attribute__((ext_vector_type(4))) float f32x4;

__device__ __forceinline__ float bf2f(ushort u) {
    unsigned v = ((unsigned)u) << 16;
    return __builtin_bit_cast(float, v);
}
__device__ __forceinline__ ushort f2bf(float f) {
    unsigned u = __builtin_bit_cast(unsigned, f);
    u += 0x7fffu + ((u >> 16) & 1u);   // RNE
    return (ushort)(u >> 16);
}
__device__ __forceinline__ short8 brelu(short8 v) {
    #pragma unroll
    for (int i = 0; i < 8; ++i) v[i] = (v[i] < (short)0) ? (short)0 : v[i];
    return v;
}

// ---------------------------------------------------------------------------
// Weight prep: f32 [K][Nin] -> bf16 subtiled [K/8][64][8] (cols >= Nin zero)
// ---------------------------------------------------------------------------
__global__ void k_w_subtile(const float* __restrict__ w, ushort* __restrict__ out,
                            int K, int Nin)
{
    int t = blockIdx.x * 256 + threadIdx.x;
    if (t >= K * 64) return;
    int k = t >> 6, c = t & 63;
    float v = (c < Nin) ? w[k * Nin + c] : 0.f;
    out[((k >> 3) * 64 + c) * 8 + (k & 7)] = f2bf(v);
}

// ---------------------------------------------------------------------------
// x = x_in @ node_emb_w[32,64] + b
// ---------------------------------------------------------------------------
__global__ __launch_bounds__(256) void k_node_emb(const float* __restrict__ xin,
                                                  const float* __restrict__ w,
                                                  const float* __restrict__ b,
                                                  float* __restrict__ xout)
{
    int idx = blockIdx.x * 256 + threadIdx.x;
    int n = idx >> 6, j = idx & 63;
    const float* xr = xin + (size_t)n * 32;
    float t = b[j];
    #pragma unroll
    for (int k = 0; k < 32; ++k) t = fmaf(xr[k], w[k * 64 + j], t);
    xout[idx] = t;
}

// ---------------------------------------------------------------------------
// e = edge_attr @ edge_emb_w[16,64] + b   -> bf16 master eb
// ---------------------------------------------------------------------------
__global__ __launch_bounds__(256) void k_edge_emb(const float* __restrict__ ein,
                                                  const float* __restrict__ w,
                                                  const float* __restrict__ b,
                                                  ushort* __restrict__ eb)
{
    int idx = blockIdx.x * 256 + threadIdx.x;
    int eid = idx >> 6, j = idx & 63;
    const float* er = ein + (size_t)eid * 16;
    float t = b[j];
    #pragma unroll
    for (int k = 0; k < 16; ++k) t = fmaf(er[k], w[k * 64 + j], t);
    eb[idx] = f2bf(t);
}

// ---------------------------------------------------------------------------
// msg = relu(x[src] + e @ lw + lb); agg[dst] += msg   (wave per edge, lane=ch)
// ---------------------------------------------------------------------------
__global__ __launch_bounds__(256) void k_msg(const float* __restrict__ x,
                                             const ushort* __restrict__ eb,
                                             const int* __restrict__ src,
                                             const int* __restrict__ dst,
                                             const float* __restrict__ lw,
                                             const float* __restrict__ lb,
                                             float* __restrict__ agg)
{
    __shared__ float wlds[64 * 64];
    __shared__ float ebuf[4][64];
    int tid = threadIdx.x;
    int w = tid >> 6, j = tid & 63;
    for (int i = tid; i < 64 * 64; i += 256) wlds[i] = lw[i];
    float bj = lb[j];
    __syncthreads();
    for (int base = blockIdx.x * 4; base < NE; base += gridDim.x * 4) {
        int edge = base + w;
        ebuf[w][j] = bf2f(eb[(size_t)edge * 64 + j]);
        __syncthreads();
        float t = bj;
        #pragma unroll 8
        for (int k = 0; k < 64; ++k) t = fmaf(ebuf[w][k], wlds[k * 64 + j], t);
        int s = src[edge], d = dst[edge];
        float m = fmaxf(x[(size_t)s * 64 + j] + t, 0.f);
        unsafeAtomicAdd(&agg[(size_t)d * 64 + j], m);
        __syncthreads();
    }
}

// ---------------------------------------------------------------------------
// h = relu((x+agg)@w1+b1)@w2+b2 (in place over agg buffer), + BN partial sums
// ---------------------------------------------------------------------------
__global__ __launch_bounds__(256) void k_conv(const float* __restrict__ x,
                                              float* __restrict__ hio,
                                              const float* __restrict__ w1g,
                                              const float* __restrict__ b1,
                                              const float* __restrict__ w2g,
                                              const float* __restrict__ b2,
                                              float* __restrict__ stats)
{
    __shared__ float w1[64 * 64];
    __shared__ float w2[64 * 64];
    __shared__ float buf[4][64];
    __shared__ float red[2][4][64];
    int tid = threadIdx.x, w = tid >> 6, j = tid & 63;
    for (int i = tid; i < 64 * 64; i += 256) { w1[i] = w1g[i]; w2[i] = w2g[i]; }
    float b1j = b1[j], b2j = b2[j];
    __syncthreads();
    float s1 = 0.f, s2 = 0.f;
    for (int base = blockIdx.x * 4; base < NN; base += gridDim.x * 4) {
        int n = base + w;
        float hp = x[(size_t)n * 64 + j] + hio[(size_t)n * 64 + j];
        buf[w][j] = hp;
        __syncthreads();
        float h1 = b1j;
        #pragma unroll 8
        for (int k = 0; k < 64; ++k) h1 = fmaf(buf[w][k], w1[k * 64 + j], h1);
        h1 = fmaxf(h1, 0.f);
        __syncthreads();
        buf[w][j] = h1;
        __syncthreads();
        float h2 = b2j;
        #pragma unroll 8
        for (int k = 0; k < 64; ++k) h2 = fmaf(buf[w][k], w2[k * 64 + j], h2);
        hio[(size_t)n * 64 + j] = h2;
        s1 += h2;
        s2 += h2 * h2;
        __syncthreads();
    }
    red[0][w][j] = s1;
    red[1][w][j] = s2;
    __syncthreads();
    if (w == 0) {
        float a = red[0][0][j] + red[0][1][j] + red[0][2][j] + red[0][3][j];
        float c = red[1][0][j] + red[1][1][j] + red[1][2][j] + red[1][3][j];
        unsafeAtomicAdd(&stats[j], a);
        unsafeAtomicAdd(&stats[64 + j], c);
    }
}

__global__ void k_bnfin(float* __restrict__ stats,
                        const float* __restrict__ gamma,
                        const float* __restrict__ beta)
{
    int j = threadIdx.x;
    float mu = stats[j] * (1.f / NN);
    float var = stats[64 + j] * (1.f / NN) - mu * mu;
    float a = gamma[j] * rsqrtf(var + 1e-5f);
    stats[128 + j] = a;
    stats[192 + j] = beta[j] - mu * a;
}

// ---------------------------------------------------------------------------
// x = (x + relu(h*a+c))/2 ; also write bf16 mirror xb
// ---------------------------------------------------------------------------
__global__ __launch_bounds__(256) void k_xupd(float* __restrict__ x,
                                              const float* __restrict__ h,
                                              const float* __restrict__ stats,
                                              ushort* __restrict__ xb)
{
    int idx = blockIdx.x * 256 + threadIdx.x;
    int j = idx & 63;
    float r = fmaxf(fmaf(h[idx], stats[128 + j], stats[192 + j]), 0.f);
    float xn = (x[idx] + r) * 0.5f;
    x[idx] = xn;
    xb[idx] = f2bf(xn);
}

// ---------------------------------------------------------------------------
// e += 0.5*( relu(cat(x[s],x[d],e)@w1+b1) @ w2 + b2 )   [MFMA bf16]
// wave per 16-edge tile; A-frags gathered straight from global;
// weights pre-subtiled [k/8][col][8] -> conflict-free ds_read_b128.
// ---------------------------------------------------------------------------
__global__ __launch_bounds__(256) void k_emlp_mfma(
    const ushort* __restrict__ xb, ushort* __restrict__ eb,
    const int* __restrict__ src, const int* __restrict__ dst,
    const ushort* __restrict__ w1s, const float* __restrict__ b1,
    const ushort* __restrict__ w2s, const float* __restrict__ b2)
{
    __shared__ ushort w1l[192 * 64];
    __shared__ ushort w2l[64 * 64];
    __shared__ ushort h1l[4][1024];   // per-wave H1 subtile [kb][row][8]
    int tid = threadIdx.x;
    #pragma unroll
    for (int i = 0; i < 6; ++i)
        *(short8*)&w1l[(i * 256 + tid) * 8] = *(const short8*)&w1s[(i * 256 + tid) * 8];
    #pragma unroll
    for (int i = 0; i < 2; ++i)
        *(short8*)&w2l[(i * 256 + tid) * 8] = *(const short8*)&w2s[(i * 256 + tid) * 8];
    __syncthreads();

    int wid = tid >> 6, lane = tid & 63;
    int c = lane & 15, kg = lane >> 4;

    short8 w2f[2][4];                 // GEMM2 weights in registers
    #pragma unroll
    for (int ks = 0; ks < 2; ++ks)
        #pragma unroll
        for (int nt = 0; nt < 4; ++nt)
            w2f[ks][nt] = *(const short8*)&w2l[((ks * 4 + kg) * 64 + nt * 16 + c) * 8];

    float b1v[4], b2v[4];
    #pragma unroll
    for (int nt = 0; nt < 4; ++nt) { b1v[nt] = b1[nt * 16 + c]; b2v[nt] = b2[nt * 16 + c]; }

    ushort* hl = h1l[wid];

    #pragma unroll 1
    for (int t4 = 0; t4 < 4; ++t4) {
        int e0 = blockIdx.x * 256 + wid * 64 + t4 * 16;
        int myedge = e0 + c;          // A-frag row = lane&15
        int s = src[myedge], d = dst[myedge];
        const ushort* xs = xb + (size_t)s * 64;
        const ushort* xd = xb + (size_t)d * 64;
        const ushort* ee = eb + (size_t)myedge * 64;
        short8 a[6];
        a[0] = *(const short8*)(xs + kg * 8);
        a[1] = *(const short8*)(xs + 32 + kg * 8);
        a[2] = *(const short8*)(xd + kg * 8);
        a[3] = *(const short8*)(xd + 32 + kg * 8);
        a[4] = *(const short8*)(ee + kg * 8);
        a[5] = *(const short8*)(ee + 32 + kg * 8);

        f32x4 acc[4];
        #pragma unroll
        for (int nt = 0; nt < 4; ++nt) acc[nt] = f32x4{b1v[nt], b1v[nt], b1v[nt], b1v[nt]};
        #pragma unroll
        for (int ks = 0; ks < 6; ++ks) {
            #pragma unroll
            for (int nt = 0; nt < 4; ++nt) {
                short8 bf = *(const short8*)&w1l[((ks * 4 + kg) * 64 + nt * 16 + c) * 8];
                acc[nt] = __builtin_amdgcn_mfma_f32_16x16x32_bf16(a[ks], bf, acc[nt], 0, 0, 0);
            }
        }
        // relu -> bf16 -> per-wave LDS subtile (C row=(lane>>4)*4+i, col=lane&15)
        #pragma unroll
        for (int nt = 0; nt < 4; ++nt) {
            #pragma unroll
            for (int i = 0; i < 4; ++i) {
                int rr = kg * 4 + i, cc = nt * 16 + c;
                hl[((cc >> 3) * 16 + rr) * 8 + (cc & 7)] = f2bf(fmaxf(acc[nt][i], 0.f));
            }
        }
        f32x4 acc2[4];
        #pragma unroll
        for (int nt = 0; nt < 4; ++nt) acc2[nt] = f32x4{b2v[nt], b2v[nt], b2v[nt], b2v[nt]};
        #pragma unroll
        for (int ks = 0; ks < 2; ++ks) {
            short8 ha = *(const short8*)&hl[((ks * 4 + kg) * 16 + c) * 8];
            #pragma unroll
            for (int nt = 0; nt < 4; ++nt)
                acc2[nt] = __builtin_amdgcn_mfma_f32_16x16x32_bf16(ha, w2f[ks][nt], acc2[nt], 0, 0, 0);
        }
        #pragma unroll
        for (int nt = 0; nt < 4; ++nt) {
            #pragma unroll
            for (int i = 0; i < 4; ++i) {
                int rr = kg * 4 + i, cc = nt * 16 + c;
                size_t off = (size_t)(e0 + rr) * 64 + cc;
                eb[off] = f2bf(bf2f(eb[off]) + 0.5f * acc2[nt][i]);
            }
        }
    }
}

// ---------------------------------------------------------------------------
// readout: H = relu([relu(x_s++x_d), e] @ m1w + b1) via MFMA (N padded 50->64),
// then per-lane 50->25->1 with wave-uniform weight loads.
// ---------------------------------------------------------------------------
__global__ __launch_bounds__(256) void k_readout_mfma(
    const ushort* __restrict__ xb, const ushort* __restrict__ eb,
    const int* __restrict__ src, const int* __restrict__ dst,
    const ushort* __restrict__ w1s, const float* __restrict__ b1,
    const float* __restrict__ w2, const float* __restrict__ b2,
    const float* __restrict__ w3, const float* __restrict__ b3,
    float* __restrict__ logit)
{
    __shared__ ushort w1l[192 * 64];
    __shared__ ushort hw[4][64 * 50];
    int tid = threadIdx.x;
    #pragma unroll
    for (int i = 0; i < 6; ++i)
        *(short8*)&w1l[(i * 256 + tid) * 8] = *(const short8*)&w1s[(i * 256 + tid) * 8];
    __syncthreads();

    int wid = tid >> 6, lane = tid & 63;
    int c = lane & 15, kg = lane >> 4;
    float b1v[4];
    #pragma unroll
    for (int nt = 0; nt < 4; ++nt) b1v[nt] = (nt * 16 + c < 50) ? b1[nt * 16 + c] : 0.f;

    #pragma unroll 1
    for (int t4 = 0; t4 < 4; ++t4) {
        int e0 = blockIdx.x * 256 + wid * 64 + t4 * 16;
        int myedge = e0 + c;
        int s = src[myedge], d = dst[myedge];
        const ushort* xs = xb + (size_t)s * 64;
        const ushort* xd = xb + (size_t)d * 64;
        const ushort* ee = eb + (size_t)myedge * 64;
        short8 a[6];
        a[0] = brelu(*(const short8*)(xs + kg * 8));
        a[1] = brelu(*(const short8*)(xs + 32 + kg * 8));
        a[2] = brelu(*(const short8*)(xd + kg * 8));
        a[3] = brelu(*(const short8*)(xd + 32 + kg * 8));
        a[4] = *(const short8*)(ee + kg * 8);
        a[5] = *(const short8*)(ee + 32 + kg * 8);

        f32x4 acc[4];
        #pragma unroll
        for (int nt = 0; nt < 4; ++nt) acc[nt] = f32x4{b1v[nt], b1v[nt], b1v[nt], b1v[nt]};
        #pragma unroll
        for (int ks = 0; ks < 6; ++ks) {
            #pragma unroll
            for (int nt = 0; nt < 4; ++nt) {
                short8 bf = *(const short8*)&w1l[((ks * 4 + kg) * 64 + nt * 16 + c) * 8];
                acc[nt] = __builtin_amdgcn_mfma_f32_16x16x32_bf16(a[ks], bf, acc[nt], 0, 0, 0);
            }
        }
        #pragma unroll
        for (int nt = 0; nt < 4; ++nt) {
            #pragma unroll
            for (int i = 0; i < 4; ++i) {
                int rr = kg * 4 + i, cc = nt * 16 + c;
                if (cc < 50)
                    hw[wid][(t4 * 16 + rr) * 50 + cc] = f2bf(fmaxf(acc[nt][i], 0.f));
            }
        }
    }
    // stage 2+3: lane per edge (same wave's rows -> no barrier needed)
    int edge = blockIdx.x * 256 + wid * 64 + lane;
    const ushort* hrow = &hw[wid][lane * 50];
    float a25[25];
    #pragma unroll
    for (int j = 0; j < 25; ++j) a25[j] = b2[j];
    #pragma unroll 2
    for (int k = 0; k < 50; ++k) {
        float hv = bf2f(hrow[k]);
        #pragma unroll
        for (int j = 0; j < 25; ++j) a25[j] = fmaf(hv, w2[k * 25 + j], a25[j]);
    }
    float lg = b3[0];
    #pragma unroll
    for (int k = 0; k < 25; ++k) lg = fmaf(fmaxf(a25[k], 0.f), w3[k], lg);
    logit[edge] = lg;
}

// ---------------------------------------------------------------------------
extern "C" void kernel_launch(void* const* d_in, const int* in_sizes, int n_in,
                              void* d_out, int out_size, void* d_ws, size_t ws_size,
                              hipStream_t stream)
{
    const float* x_in  = (const float*)d_in[0];
    const float* eattr = (const float*)d_in[1];
    const int*   src   = (const int*)d_in[2];
    const int*   dst   = (const int*)d_in[3];
    const float* n_w   = (const float*)d_in[4];
    const float* n_b   = (const float*)d_in[5];
    const float* e_w   = (const float*)d_in[6];
    const float* e_b   = (const float*)d_in[7];
    const float* lw    = (const float*)d_in[8];
    const float* lb    = (const float*)d_in[9];
    const float* cw1   = (const float*)d_in[10];
    const float* cb1   = (const float*)d_in[11];
    const float* cw2   = (const float*)d_in[12];
    const float* cb2   = (const float*)d_in[13];
    const float* ew1   = (const float*)d_in[14];
    const float* eb1   = (const float*)d_in[15];
    const float* ew2   = (const float*)d_in[16];
    const float* eb2   = (const float*)d_in[17];
    const float* gam   = (const float*)d_in[18];
    const float* bet   = (const float*)d_in[19];
    const float* m1w   = (const float*)d_in[20];
    const float* m1b   = (const float*)d_in[21];
    const float* m2w   = (const float*)d_in[22];
    const float* m2b   = (const float*)d_in[23];
    const float* m3w   = (const float*)d_in[24];
    const float* m3b   = (const float*)d_in[25];

    float* xbuf  = (float*)d_out;                  // [NN,64] f32 master (output 0)
    float* logit = xbuf + (size_t)NN * 64;         // [NE]

    ushort* eb   = (ushort*)d_ws;                  // [NE,64] bf16 e master
    float*  tmp  = (float*)(eb + (size_t)NE * 64); // [NN,64] agg -> h
    float*  stats = tmp + (size_t)NN * 64;         // 256
    ushort* w1s  = (ushort*)(stats + 256);         // 2*192*64
    ushort* w2s  = w1s + 2 * 192 * 64;             // 2*64*64
    ushort* m1s  = w2s + 2 * 64 * 64;              // 192*64
    ushort* xb   = m1s + 192 * 64;                 // [NN,64] bf16 mirror of x

    // weight prep (bf16 + subtile)
    k_w_subtile<<<48, 256, 0, stream>>>(ew1,            w1s,            192, 64);
    k_w_subtile<<<48, 256, 0, stream>>>(ew1 + 192 * 64, w1s + 192 * 64, 192, 64);
    k_w_subtile<<<16, 256, 0, stream>>>(ew2,            w2s,            64, 64);
    k_w_subtile<<<16, 256, 0, stream>>>(ew2 + 64 * 64,  w2s + 64 * 64,  64, 64);
    k_w_subtile<<<48, 256, 0, stream>>>(m1w,            m1s,            192, 50);

    k_node_emb<<<NN * 64 / 256, 256, 0, stream>>>(x_in, n_w, n_b, xbuf);
    k_edge_emb<<<NE * 64 / 256, 256, 0, stream>>>(eattr, e_w, e_b, eb);

    for (int l = 0; l < 2; ++l) {
        hipMemsetAsync(tmp, 0, (size_t)NN * 64 * sizeof(float), stream);
        hipMemsetAsync(stats, 0, 256 * sizeof(float), stream);
        k_msg<<<2048, 256, 0, stream>>>(xbuf, eb, src, dst,
                                        lw + l * 64 * 64, lb + l * 64, tmp);
        k_conv<<<2048, 256, 0, stream>>>(xbuf, tmp, cw1 + l * 64 * 64, cb1 + l * 64,
                                         cw2 + l * 64 * 64, cb2 + l * 64, stats);
        k_bnfin<<<1, 64, 0, stream>>>(stats, gam + l * 64, bet + l * 64);
        k_xupd<<<NN * 64 / 256, 256, 0, stream>>>(xbuf, tmp, stats, xb);
        k_emlp_mfma<<<NE / 256, 256, 0, stream>>>(xb, eb, src, dst,
                                                  w1s + l * 192 * 64, eb1 + l * 64,
                                                  w2s + l * 64 * 64, eb2 + l * 64);
    }

    k_readout_mfma<<<NE / 256, 256, 0, stream>>>(xb, eb, src, dst,
                                                 m1s, m1b, m2w, m2b, m3w, m3b, logit);
}

// Round 3
// 828.409 us; speedup vs baseline: 2.4360x; 1.4109x over previous
//
#include <hip/hip_runtime.h>

#define NN 100000
#define NE 640000

typedef __attribute__((ext_vector_type(8))) short short8;
typedef __attribute__((ext_vector_type(4))) float f32x4;

__device__ __forceinline__ float bf2f(ushort u) {
    unsigned v = ((unsigned)u) << 16;
    return __builtin_bit_cast(float, v);
}
__device__ __forceinline__ ushort f2bf(float f) {
    unsigned u = __builtin_bit_cast(unsigned, f);
    u += 0x7fffu + ((u >> 16) & 1u);   // RNE
    return (ushort)(u >> 16);
}
__device__ __forceinline__ short8 brelu(short8 v) {
    #pragma unroll
    for (int i = 0; i < 8; ++i) v[i] = (v[i] < (short)0) ? (short)0 : v[i];
    return v;
}

// ---------------------------------------------------------------------------
// Weight prep: f32 [K][Nin] -> bf16 subtiled [K/8][64][8] (cols >= Nin zero)
// ---------------------------------------------------------------------------
__global__ void k_w_subtile(const float* __restrict__ w, ushort* __restrict__ out,
                            int K, int Nin)
{
    int t = blockIdx.x * 256 + threadIdx.x;
    if (t >= K * 64) return;
    int k = t >> 6, c = t & 63;
    float v = (c < Nin) ? w[k * Nin + c] : 0.f;
    out[((k >> 3) * 64 + c) * 8 + (k & 7)] = f2bf(v);
}

// msg weight: [[I64],[lw]] as [128,64] subtiled
__global__ void k_w_msg(const float* __restrict__ lw, ushort* __restrict__ out)
{
    int t = blockIdx.x * 256 + threadIdx.x;   // 128*64
    if (t >= 128 * 64) return;
    int k = t >> 6, c = t & 63;
    float v = (k < 64) ? (k == c ? 1.f : 0.f) : lw[(k - 64) * 64 + c];
    out[((k >> 3) * 64 + c) * 8 + (k & 7)] = f2bf(v);
}

// ---------------------------------------------------------------------------
// x = x_in @ node_emb_w[32,64] + b  (f32 master + bf16 mirror)
// ---------------------------------------------------------------------------
__global__ __launch_bounds__(256) void k_node_emb(const float* __restrict__ xin,
                                                  const float* __restrict__ w,
                                                  const float* __restrict__ b,
                                                  float* __restrict__ xout,
                                                  ushort* __restrict__ xb)
{
    int idx = blockIdx.x * 256 + threadIdx.x;
    int n = idx >> 6, j = idx & 63;
    const float* xr = xin + (size_t)n * 32;
    float t = b[j];
    #pragma unroll
    for (int k = 0; k < 32; ++k) t = fmaf(xr[k], w[k * 64 + j], t);
    xout[idx] = t;
    xb[idx] = f2bf(t);
}

// ---------------------------------------------------------------------------
// e = edge_attr @ edge_emb_w[16,64] + b   -> bf16 master eb
// ---------------------------------------------------------------------------
__global__ __launch_bounds__(256) void k_edge_emb(const float* __restrict__ ein,
                                                  const float* __restrict__ w,
                                                  const float* __restrict__ b,
                                                  ushort* __restrict__ eb)
{
    int idx = blockIdx.x * 256 + threadIdx.x;
    int eid = idx >> 6, j = idx & 63;
    const float* er = ein + (size_t)eid * 16;
    float t = b[j];
    #pragma unroll
    for (int k = 0; k < 16; ++k) t = fmaf(er[k], w[k * 64 + j], t);
    eb[idx] = f2bf(t);
}

// ---------------------------------------------------------------------------
// msg = relu([x[src]|e] @ [[I],[lw]] + lb); agg[dst] += msg   [MFMA bf16]
// wave per 16-edge tile; A gathered from global; coalesced 64B atomic scatter
// ---------------------------------------------------------------------------
__global__ __launch_bounds__(256) void k_msg_mfma(
    const ushort* __restrict__ xb, const ushort* __restrict__ eb,
    const int* __restrict__ src, const int* __restrict__ dst,
    const ushort* __restrict__ wms, const float* __restrict__ lb,
    float* __restrict__ agg)
{
    __shared__ ushort wl[128 * 64];
    int tid = threadIdx.x;
    #pragma unroll
    for (int i = 0; i < 4; ++i)
        *(short8*)&wl[(i * 256 + tid) * 8] = *(const short8*)&wms[(i * 256 + tid) * 8];
    __syncthreads();

    int wid = tid >> 6, lane = tid & 63;
    int c = lane & 15, kg = lane >> 4;
    float bv[4];
    #pragma unroll
    for (int nt = 0; nt < 4; ++nt) bv[nt] = lb[nt * 16 + c];

    #pragma unroll 1
    for (int t4 = 0; t4 < 4; ++t4) {
        int e0 = blockIdx.x * 256 + wid * 64 + t4 * 16;
        int myedge = e0 + c;
        const ushort* xs = xb + (size_t)src[myedge] * 64;
        const ushort* ee = eb + (size_t)myedge * 64;
        short8 a[4];
        a[0] = *(const short8*)(xs + kg * 8);
        a[1] = *(const short8*)(xs + 32 + kg * 8);
        a[2] = *(const short8*)(ee + kg * 8);
        a[3] = *(const short8*)(ee + 32 + kg * 8);

        f32x4 acc[4];
        #pragma unroll
        for (int nt = 0; nt < 4; ++nt) acc[nt] = f32x4{bv[nt], bv[nt], bv[nt], bv[nt]};
        #pragma unroll
        for (int ks = 0; ks < 4; ++ks) {
            #pragma unroll
            for (int nt = 0; nt < 4; ++nt) {
                short8 bf = *(const short8*)&wl[((ks * 4 + kg) * 64 + nt * 16 + c) * 8];
                acc[nt] = __builtin_amdgcn_mfma_f32_16x16x32_bf16(a[ks], bf, acc[nt], 0, 0, 0);
            }
        }
        int drow[4];
        #pragma unroll
        for (int i = 0; i < 4; ++i) drow[i] = dst[e0 + kg * 4 + i];
        #pragma unroll
        for (int nt = 0; nt < 4; ++nt) {
            #pragma unroll
            for (int i = 0; i < 4; ++i) {
                float m = fmaxf(acc[nt][i], 0.f);
                unsafeAtomicAdd(&agg[(size_t)drow[i] * 64 + nt * 16 + c], m);
            }
        }
    }
}

// ---------------------------------------------------------------------------
// h = relu((x+agg)@w1+b1)@w2+b2  [MFMA bf16], writes h f32 + BN partial sums
// ---------------------------------------------------------------------------
__global__ __launch_bounds__(256) void k_conv_mfma(
    const float* __restrict__ x, float* __restrict__ hio,
    const ushort* __restrict__ w1s, const float* __restrict__ b1,
    const ushort* __restrict__ w2s, const float* __restrict__ b2,
    float* __restrict__ stats)
{
    __shared__ ushort w1l[64 * 64];
    __shared__ ushort w2l[64 * 64];
    __shared__ ushort h1l[4][1024];
    __shared__ float red[2][4][64];
    int tid = threadIdx.x;
    #pragma unroll
    for (int i = 0; i < 2; ++i) {
        *(short8*)&w1l[(i * 256 + tid) * 8] = *(const short8*)&w1s[(i * 256 + tid) * 8];
        *(short8*)&w2l[(i * 256 + tid) * 8] = *(const short8*)&w2s[(i * 256 + tid) * 8];
    }
    __syncthreads();

    int wid = tid >> 6, lane = tid & 63;
    int c = lane & 15, kg = lane >> 4;

    short8 w2f[2][4];
    #pragma unroll
    for (int ks = 0; ks < 2; ++ks)
        #pragma unroll
        for (int nt = 0; nt < 4; ++nt)
            w2f[ks][nt] = *(const short8*)&w2l[((ks * 4 + kg) * 64 + nt * 16 + c) * 8];

    float b1v[4], b2v[4];
    #pragma unroll
    for (int nt = 0; nt < 4; ++nt) { b1v[nt] = b1[nt * 16 + c]; b2v[nt] = b2[nt * 16 + c]; }

    float s1[4] = {0.f, 0.f, 0.f, 0.f}, s2[4] = {0.f, 0.f, 0.f, 0.f};
    ushort* hl = h1l[wid];

    int t = blockIdx.x * 4 + wid;          // tile of 16 nodes; NN%16==0
    if (t < NN / 16) {
        int n0 = t * 16;
        const float* xr = x + (size_t)(n0 + c) * 64;
        const float* hr = hio + (size_t)(n0 + c) * 64;
        short8 a[2];
        #pragma unroll
        for (int ks = 0; ks < 2; ++ks) {
            f32x4 u0 = *(const f32x4*)(xr + ks * 32 + kg * 8);
            f32x4 u1 = *(const f32x4*)(xr + ks * 32 + kg * 8 + 4);
            f32x4 v0 = *(const f32x4*)(hr + ks * 32 + kg * 8);
            f32x4 v1 = *(const f32x4*)(hr + ks * 32 + kg * 8 + 4);
            #pragma unroll
            for (int j = 0; j < 4; ++j) {
                a[ks][j]     = (short)f2bf(u0[j] + v0[j]);
                a[ks][4 + j] = (short)f2bf(u1[j] + v1[j]);
            }
        }
        f32x4 acc[4];
        #pragma unroll
        for (int nt = 0; nt < 4; ++nt) acc[nt] = f32x4{b1v[nt], b1v[nt], b1v[nt], b1v[nt]};
        #pragma unroll
        for (int ks = 0; ks < 2; ++ks) {
            #pragma unroll
            for (int nt = 0; nt < 4; ++nt) {
                short8 bf = *(const short8*)&w1l[((ks * 4 + kg) * 64 + nt * 16 + c) * 8];
                acc[nt] = __builtin_amdgcn_mfma_f32_16x16x32_bf16(a[ks], bf, acc[nt], 0, 0, 0);
            }
        }
        #pragma unroll
        for (int nt = 0; nt < 4; ++nt) {
            #pragma unroll
            for (int i = 0; i < 4; ++i) {
                int rr = kg * 4 + i, cc = nt * 16 + c;
                hl[((cc >> 3) * 16 + rr) * 8 + (cc & 7)] = f2bf(fmaxf(acc[nt][i], 0.f));
            }
        }
        f32x4 acc2[4];
        #pragma unroll
        for (int nt = 0; nt < 4; ++nt) acc2[nt] = f32x4{b2v[nt], b2v[nt], b2v[nt], b2v[nt]};
        #pragma unroll
        for (int ks = 0; ks < 2; ++ks) {
            short8 ha = *(const short8*)&hl[((ks * 4 + kg) * 16 + c) * 8];
            #pragma unroll
            for (int nt = 0; nt < 4; ++nt)
                acc2[nt] = __builtin_amdgcn_mfma_f32_16x16x32_bf16(ha, w2f[ks][nt], acc2[nt], 0, 0, 0);
        }
        #pragma unroll
        for (int nt = 0; nt < 4; ++nt) {
            #pragma unroll
            for (int i = 0; i < 4; ++i) {
                int rr = kg * 4 + i, cc = nt * 16 + c;
                float h2 = acc2[nt][i];
                hio[(size_t)(n0 + rr) * 64 + cc] = h2;
                s1[nt] += h2;
                s2[nt] += h2 * h2;
            }
        }
    }
    // cross-kg reduce, then per-block reduce, then one atomic set per block
    #pragma unroll
    for (int nt = 0; nt < 4; ++nt) {
        float v1 = s1[nt], v2 = s2[nt];
        v1 += __shfl_xor(v1, 16); v1 += __shfl_xor(v1, 32);
        v2 += __shfl_xor(v2, 16); v2 += __shfl_xor(v2, 32);
        s1[nt] = v1; s2[nt] = v2;
    }
    if (lane < 16) {
        #pragma unroll
        for (int nt = 0; nt < 4; ++nt) {
            red[0][wid][nt * 16 + c] = s1[nt];
            red[1][wid][nt * 16 + c] = s2[nt];
        }
    }
    __syncthreads();
    if (wid == 0) {
        float a = red[0][0][lane] + red[0][1][lane] + red[0][2][lane] + red[0][3][lane];
        float b = red[1][0][lane] + red[1][1][lane] + red[1][2][lane] + red[1][3][lane];
        unsafeAtomicAdd(&stats[lane], a);
        unsafeAtomicAdd(&stats[64 + lane], b);
    }
}

__global__ void k_bnfin(float* __restrict__ stats,
                        const float* __restrict__ gamma,
                        const float* __restrict__ beta)
{
    int j = threadIdx.x;
    float mu = stats[j] * (1.f / NN);
    float var = stats[64 + j] * (1.f / NN) - mu * mu;
    float a = gamma[j] * rsqrtf(var + 1e-5f);
    stats[128 + j] = a;
    stats[192 + j] = beta[j] - mu * a;
}

// ---------------------------------------------------------------------------
// x = (x + relu(h*a+c))/2 ; also write bf16 mirror xb
// ---------------------------------------------------------------------------
__global__ __launch_bounds__(256) void k_xupd(float* __restrict__ x,
                                              const float* __restrict__ h,
                                              const float* __restrict__ stats,
                                              ushort* __restrict__ xb)
{
    int idx = blockIdx.x * 256 + threadIdx.x;
    int j = idx & 63;
    float r = fmaxf(fmaf(h[idx], stats[128 + j], stats[192 + j]), 0.f);
    float xn = (x[idx] + r) * 0.5f;
    x[idx] = xn;
    xb[idx] = f2bf(xn);
}

// ---------------------------------------------------------------------------
// e += 0.5*( relu(cat(x[s],x[d],e)@w1+b1) @ w2 + b2 )   [MFMA bf16]
// ---------------------------------------------------------------------------
__global__ __launch_bounds__(256) void k_emlp_mfma(
    const ushort* __restrict__ xb, ushort* __restrict__ eb,
    const int* __restrict__ src, const int* __restrict__ dst,
    const ushort* __restrict__ w1s, const float* __restrict__ b1,
    const ushort* __restrict__ w2s, const float* __restrict__ b2)
{
    __shared__ ushort w1l[192 * 64];
    __shared__ ushort w2l[64 * 64];
    __shared__ ushort h1l[4][1024];
    int tid = threadIdx.x;
    #pragma unroll
    for (int i = 0; i < 6; ++i)
        *(short8*)&w1l[(i * 256 + tid) * 8] = *(const short8*)&w1s[(i * 256 + tid) * 8];
    #pragma unroll
    for (int i = 0; i < 2; ++i)
        *(short8*)&w2l[(i * 256 + tid) * 8] = *(const short8*)&w2s[(i * 256 + tid) * 8];
    __syncthreads();

    int wid = tid >> 6, lane = tid & 63;
    int c = lane & 15, kg = lane >> 4;

    short8 w2f[2][4];
    #pragma unroll
    for (int ks = 0; ks < 2; ++ks)
        #pragma unroll
        for (int nt = 0; nt < 4; ++nt)
            w2f[ks][nt] = *(const short8*)&w2l[((ks * 4 + kg) * 64 + nt * 16 + c) * 8];

    float b1v[4], b2v[4];
    #pragma unroll
    for (int nt = 0; nt < 4; ++nt) { b1v[nt] = b1[nt * 16 + c]; b2v[nt] = b2[nt * 16 + c]; }

    ushort* hl = h1l[wid];

    #pragma unroll 1
    for (int t4 = 0; t4 < 4; ++t4) {
        int e0 = blockIdx.x * 256 + wid * 64 + t4 * 16;
        int myedge = e0 + c;
        int s = src[myedge], d = dst[myedge];
        const ushort* xs = xb + (size_t)s * 64;
        const ushort* xd = xb + (size_t)d * 64;
        const ushort* ee = eb + (size_t)myedge * 64;
        short8 a[6];
        a[0] = *(const short8*)(xs + kg * 8);
        a[1] = *(const short8*)(xs + 32 + kg * 8);
        a[2] = *(const short8*)(xd + kg * 8);
        a[3] = *(const short8*)(xd + 32 + kg * 8);
        a[4] = *(const short8*)(ee + kg * 8);
        a[5] = *(const short8*)(ee + 32 + kg * 8);

        f32x4 acc[4];
        #pragma unroll
        for (int nt = 0; nt < 4; ++nt) acc[nt] = f32x4{b1v[nt], b1v[nt], b1v[nt], b1v[nt]};
        #pragma unroll
        for (int ks = 0; ks < 6; ++ks) {
            #pragma unroll
            for (int nt = 0; nt < 4; ++nt) {
                short8 bf = *(const short8*)&w1l[((ks * 4 + kg) * 64 + nt * 16 + c) * 8];
                acc[nt] = __builtin_amdgcn_mfma_f32_16x16x32_bf16(a[ks], bf, acc[nt], 0, 0, 0);
            }
        }
        #pragma unroll
        for (int nt = 0; nt < 4; ++nt) {
            #pragma unroll
            for (int i = 0; i < 4; ++i) {
                int rr = kg * 4 + i, cc = nt * 16 + c;
                hl[((cc >> 3) * 16 + rr) * 8 + (cc & 7)] = f2bf(fmaxf(acc[nt][i], 0.f));
            }
        }
        f32x4 acc2[4];
        #pragma unroll
        for (int nt = 0; nt < 4; ++nt) acc2[nt] = f32x4{b2v[nt], b2v[nt], b2v[nt], b2v[nt]};
        #pragma unroll
        for (int ks = 0; ks < 2; ++ks) {
            short8 ha = *(const short8*)&hl[((ks * 4 + kg) * 16 + c) * 8];
            #pragma unroll
            for (int nt = 0; nt < 4; ++nt)
                acc2[nt] = __builtin_amdgcn_mfma_f32_16x16x32_bf16(ha, w2f[ks][nt], acc2[nt], 0, 0, 0);
        }
        #pragma unroll
        for (int nt = 0; nt < 4; ++nt) {
            #pragma unroll
            for (int i = 0; i < 4; ++i) {
                int rr = kg * 4 + i, cc = nt * 16 + c;
                size_t off = (size_t)(e0 + rr) * 64 + cc;
                eb[off] = f2bf(bf2f(eb[off]) + 0.5f * acc2[nt][i]);
            }
        }
    }
}

// ---------------------------------------------------------------------------
// readout
// ---------------------------------------------------------------------------
__global__ __launch_bounds__(256) void k_readout_mfma(
    const ushort* __restrict__ xb, const ushort* __restrict__ eb,
    const int* __restrict__ src, const int* __restrict__ dst,
    const ushort* __restrict__ w1s, const float* __restrict__ b1,
    const float* __restrict__ w2, const float* __restrict__ b2,
    const float* __restrict__ w3, const float* __restrict__ b3,
    float* __restrict__ logit)
{
    __shared__ ushort w1l[192 * 64];
    __shared__ ushort hw[4][64 * 50];
    int tid = threadIdx.x;
    #pragma unroll
    for (int i = 0; i < 6; ++i)
        *(short8*)&w1l[(i * 256 + tid) * 8] = *(const short8*)&w1s[(i * 256 + tid) * 8];
    __syncthreads();

    int wid = tid >> 6, lane = tid & 63;
    int c = lane & 15, kg = lane >> 4;
    float b1v[4];
    #pragma unroll
    for (int nt = 0; nt < 4; ++nt) b1v[nt] = (nt * 16 + c < 50) ? b1[nt * 16 + c] : 0.f;

    #pragma unroll 1
    for (int t4 = 0; t4 < 4; ++t4) {
        int e0 = blockIdx.x * 256 + wid * 64 + t4 * 16;
        int myedge = e0 + c;
        int s = src[myedge], d = dst[myedge];
        const ushort* xs = xb + (size_t)s * 64;
        const ushort* xd = xb + (size_t)d * 64;
        const ushort* ee = eb + (size_t)myedge * 64;
        short8 a[6];
        a[0] = brelu(*(const short8*)(xs + kg * 8));
        a[1] = brelu(*(const short8*)(xs + 32 + kg * 8));
        a[2] = brelu(*(const short8*)(xd + kg * 8));
        a[3] = brelu(*(const short8*)(xd + 32 + kg * 8));
        a[4] = *(const short8*)(ee + kg * 8);
        a[5] = *(const short8*)(ee + 32 + kg * 8);

        f32x4 acc[4];
        #pragma unroll
        for (int nt = 0; nt < 4; ++nt) acc[nt] = f32x4{b1v[nt], b1v[nt], b1v[nt], b1v[nt]};
        #pragma unroll
        for (int ks = 0; ks < 6; ++ks) {
            #pragma unroll
            for (int nt = 0; nt < 4; ++nt) {
                short8 bf = *(const short8*)&w1l[((ks * 4 + kg) * 64 + nt * 16 + c) * 8];
                acc[nt] = __builtin_amdgcn_mfma_f32_16x16x32_bf16(a[ks], bf, acc[nt], 0, 0, 0);
            }
        }
        #pragma unroll
        for (int nt = 0; nt < 4; ++nt) {
            #pragma unroll
            for (int i = 0; i < 4; ++i) {
                int rr = kg * 4 + i, cc = nt * 16 + c;
                if (cc < 50)
                    hw[wid][(t4 * 16 + rr) * 50 + cc] = f2bf(fmaxf(acc[nt][i], 0.f));
            }
        }
    }
    int edge = blockIdx.x * 256 + wid * 64 + lane;
    const ushort* hrow = &hw[wid][lane * 50];
    float a25[25];
    #pragma unroll
    for (int j = 0; j < 25; ++j) a25[j] = b2[j];
    #pragma unroll 2
    for (int k = 0; k < 50; ++k) {
        float hv = bf2f(hrow[k]);
        #pragma unroll
        for (int j = 0; j < 25; ++j) a25[j] = fmaf(hv, w2[k * 25 + j], a25[j]);
    }
    float lg = b3[0];
    #pragma unroll
    for (int k = 0; k < 25; ++k) lg = fmaf(fmaxf(a25[k], 0.f), w3[k], lg);
    logit[edge] = lg;
}

// ---------------------------------------------------------------------------
extern "C" void kernel_launch(void* const* d_in, const int* in_sizes, int n_in,
                              void* d_out, int out_size, void* d_ws, size_t ws_size,
                              hipStream_t stream)
{
    const float* x_in  = (const float*)d_in[0];
    const float* eattr = (const float*)d_in[1];
    const int*   src   = (const int*)d_in[2];
    const int*   dst   = (const int*)d_in[3];
    const float* n_w   = (const float*)d_in[4];
    const float* n_b   = (const float*)d_in[5];
    const float* e_w   = (const float*)d_in[6];
    const float* e_b   = (const float*)d_in[7];
    const float* lw    = (const float*)d_in[8];
    const float* lb    = (const float*)d_in[9];
    const float* cw1   = (const float*)d_in[10];
    const float* cb1   = (const float*)d_in[11];
    const float* cw2   = (const float*)d_in[12];
    const float* cb2   = (const float*)d_in[13];
    const float* ew1   = (const float*)d_in[14];
    const float* eb1   = (const float*)d_in[15];
    const float* ew2   = (const float*)d_in[16];
    const float* eb2   = (const float*)d_in[17];
    const float* gam   = (const float*)d_in[18];
    const float* bet   = (const float*)d_in[19];
    const float* m1w   = (const float*)d_in[20];
    const float* m1b   = (const float*)d_in[21];
    const float* m2w   = (const float*)d_in[22];
    const float* m2b   = (const float*)d_in[23];
    const float* m3w   = (const float*)d_in[24];
    const float* m3b   = (const float*)d_in[25];

    float* xbuf  = (float*)d_out;                  // [NN,64] f32 master (output 0)
    float* logit = xbuf + (size_t)NN * 64;         // [NE]

    ushort* eb    = (ushort*)d_ws;                 // [NE,64] bf16 e master
    float*  tmp   = (float*)(eb + (size_t)NE * 64);// [NN,64] agg -> h
    float*  stats = tmp + (size_t)NN * 64;         // 256
    ushort* w1s   = (ushort*)(stats + 256);        // 2*192*64
    ushort* w2s   = w1s + 2 * 192 * 64;            // 2*64*64
    ushort* m1s   = w2s + 2 * 64 * 64;             // 192*64
    ushort* xb    = m1s + 192 * 64;                // [NN,64] bf16 mirror of x
    ushort* wms   = xb + (size_t)NN * 64;          // 2*128*64 msg weights
    ushort* cw1s  = wms + 2 * 128 * 64;            // 2*64*64
    ushort* cw2s  = cw1s + 2 * 64 * 64;            // 2*64*64

    // weight prep (bf16 + subtile)
    k_w_subtile<<<48, 256, 0, stream>>>(ew1,            w1s,            192, 64);
    k_w_subtile<<<48, 256, 0, stream>>>(ew1 + 192 * 64, w1s + 192 * 64, 192, 64);
    k_w_subtile<<<16, 256, 0, stream>>>(ew2,            w2s,            64, 64);
    k_w_subtile<<<16, 256, 0, stream>>>(ew2 + 64 * 64,  w2s + 64 * 64,  64, 64);
    k_w_subtile<<<48, 256, 0, stream>>>(m1w,            m1s,            192, 50);
    k_w_msg<<<32, 256, 0, stream>>>(lw,           wms);
    k_w_msg<<<32, 256, 0, stream>>>(lw + 64 * 64, wms + 128 * 64);
    k_w_subtile<<<16, 256, 0, stream>>>(cw1,            cw1s,           64, 64);
    k_w_subtile<<<16, 256, 0, stream>>>(cw1 + 64 * 64,  cw1s + 64 * 64, 64, 64);
    k_w_subtile<<<16, 256, 0, stream>>>(cw2,            cw2s,           64, 64);
    k_w_subtile<<<16, 256, 0, stream>>>(cw2 + 64 * 64,  cw2s + 64 * 64, 64, 64);

    k_node_emb<<<NN * 64 / 256, 256, 0, stream>>>(x_in, n_w, n_b, xbuf, xb);
    k_edge_emb<<<NE * 64 / 256, 256, 0, stream>>>(eattr, e_w, e_b, eb);

    for (int l = 0; l < 2; ++l) {
        hipMemsetAsync(tmp, 0, (size_t)NN * 64 * sizeof(float), stream);
        hipMemsetAsync(stats, 0, 256 * sizeof(float), stream);
        k_msg_mfma<<<NE / 256, 256, 0, stream>>>(xb, eb, src, dst,
                                                 wms + l * 128 * 64, lb + l * 64, tmp);
        k_conv_mfma<<<(NN / 16 + 3) / 4, 256, 0, stream>>>(
            xbuf, tmp, cw1s + l * 64 * 64, cb1 + l * 64,
            cw2s + l * 64 * 64, cb2 + l * 64, stats);
        k_bnfin<<<1, 64, 0, stream>>>(stats, gam + l * 64, bet + l * 64);
        k_xupd<<<NN * 64 / 256, 256, 0, stream>>>(xbuf, tmp, stats, xb);
        k_emlp_mfma<<<NE / 256, 256, 0, stream>>>(xb, eb, src, dst,
                                                  w1s + l * 192 * 64, eb1 + l * 64,
                                                  w2s + l * 64 * 64, eb2 + l * 64);
    }

    k_readout_mfma<<<NE / 256, 256, 0, stream>>>(xb, eb, src, dst,
                                                 m1s, m1b, m2w, m2b, m3w, m3b, logit);
}

// Round 4
// 659.002 us; speedup vs baseline: 3.0622x; 1.2571x over previous
//
#include <hip/hip_runtime.h>

#define NN 100000
#define NE 640000

typedef __attribute__((ext_vector_type(8))) short short8;
typedef __attribute__((ext_vector_type(4))) float f32x4;
typedef __attribute__((ext_vector_type(4))) ushort ushort4v;

__device__ __forceinline__ float bf2f(ushort u) {
    unsigned v = ((unsigned)u) << 16;
    return __builtin_bit_cast(float, v);
}
__device__ __forceinline__ ushort f2bf(float f) {
    unsigned u = __builtin_bit_cast(unsigned, f);
    u += 0x7fffu + ((u >> 16) & 1u);   // RNE
    return (ushort)(u >> 16);
}
__device__ __forceinline__ short8 brelu(short8 v) {
    #pragma unroll
    for (int i = 0; i < 8; ++i) v[i] = (v[i] < (short)0) ? (short)0 : v[i];
    return v;
}

// ---------------------------------------------------------------------------
// Weight prep: f32 [K][Nin] -> bf16 subtiled [K/8][64][8] (cols >= Nin zero)
// ---------------------------------------------------------------------------
__global__ void k_w_subtile(const float* __restrict__ w, ushort* __restrict__ out,
                            int K, int Nin)
{
    int t = blockIdx.x * 256 + threadIdx.x;
    if (t >= K * 64) return;
    int k = t >> 6, c = t & 63;
    float v = (c < Nin) ? w[k * Nin + c] : 0.f;
    out[((k >> 3) * 64 + c) * 8 + (k & 7)] = f2bf(v);
}

// Weight prep with K padding: f32 [Kreal][64] -> bf16 subtiled [Kpad/8][64][8]
__global__ void k_w_padk(const float* __restrict__ w, ushort* __restrict__ out,
                         int Kreal, int Kpad)
{
    int t = blockIdx.x * 256 + threadIdx.x;
    if (t >= Kpad * 64) return;
    int k = t >> 6, c = t & 63;
    float v = (k < Kreal) ? w[k * 64 + c] : 0.f;
    out[((k >> 3) * 64 + c) * 8 + (k & 7)] = f2bf(v);
}

// msg weight: [[I64],[lw]] as [128,64] subtiled
__global__ void k_w_msg(const float* __restrict__ lw, ushort* __restrict__ out)
{
    int t = blockIdx.x * 256 + threadIdx.x;   // 128*64
    if (t >= 128 * 64) return;
    int k = t >> 6, c = t & 63;
    float v = (k < 64) ? (k == c ? 1.f : 0.f) : lw[(k - 64) * 64 + c];
    out[((k >> 3) * 64 + c) * 8 + (k & 7)] = f2bf(v);
}

// ---------------------------------------------------------------------------
// x = x_in @ node_emb_w[32,64] + b   [MFMA, K=32 exact]; wave per 16-node tile
// writes f32 master + bf16 mirror via per-wave LDS bounce (coalesced stores)
// ---------------------------------------------------------------------------
__global__ __launch_bounds__(256) void k_node_emb_mfma(
    const float* __restrict__ xin, const ushort* __restrict__ ws,
    const float* __restrict__ b, float* __restrict__ xout,
    ushort* __restrict__ xb)
{
    __shared__ ushort wl[32 * 64];
    __shared__ float fbuf[4][16 * 64];
    __shared__ ushort bbuf[4][16 * 64];
    int tid = threadIdx.x;
    *(short8*)&wl[tid * 8] = *(const short8*)&ws[tid * 8];
    __syncthreads();

    int wid = tid >> 6, lane = tid & 63, c = lane & 15, kg = lane >> 4;
    int t = blockIdx.x * 4 + wid;
    if (t >= NN / 16) return;
    int n0 = t * 16;

    const float* xr = xin + (size_t)(n0 + c) * 32 + kg * 8;
    f32x4 u0 = *(const f32x4*)xr, u1 = *(const f32x4*)(xr + 4);
    short8 a;
    #pragma unroll
    for (int j = 0; j < 4; ++j) { a[j] = (short)f2bf(u0[j]); a[4 + j] = (short)f2bf(u1[j]); }

    f32x4 acc[4];
    #pragma unroll
    for (int nt = 0; nt < 4; ++nt) {
        float bv = b[nt * 16 + c];
        acc[nt] = f32x4{bv, bv, bv, bv};
        short8 bf = *(const short8*)&wl[(kg * 64 + nt * 16 + c) * 8];
        acc[nt] = __builtin_amdgcn_mfma_f32_16x16x32_bf16(a, bf, acc[nt], 0, 0, 0);
    }
    #pragma unroll
    for (int nt = 0; nt < 4; ++nt)
        #pragma unroll
        for (int i = 0; i < 4; ++i) {
            int rr = kg * 4 + i, cc = nt * 16 + c;
            float v = acc[nt][i];
            fbuf[wid][rr * 64 + cc] = v;
            bbuf[wid][rr * 64 + cc] = f2bf(v);
        }
    #pragma unroll
    for (int r = 0; r < 4; ++r) {
        int q = r * 64 + lane;           // 16B chunk of fbuf (256 chunks)
        *(f32x4*)&xout[(size_t)(n0 + (q >> 4)) * 64 + (q & 15) * 4] =
            *(f32x4*)&fbuf[wid][q * 4];
    }
    #pragma unroll
    for (int r = 0; r < 2; ++r) {
        int q = r * 64 + lane;           // 16B chunk of bbuf (128 chunks)
        *(short8*)&xb[(size_t)(n0 + (q >> 3)) * 64 + (q & 7) * 8] =
            *(short8*)&bbuf[wid][q * 8];
    }
}

// ---------------------------------------------------------------------------
// e = edge_attr @ edge_emb_w[16,64] + b  [MFMA, K padded 16->32] -> bf16 eb
// ---------------------------------------------------------------------------
__global__ __launch_bounds__(256) void k_edge_emb_mfma(
    const float* __restrict__ ein, const ushort* __restrict__ ws,
    const float* __restrict__ b, ushort* __restrict__ eb)
{
    __shared__ ushort wl[32 * 64];
    __shared__ ushort bbuf[4][16 * 64];
    int tid = threadIdx.x;
    *(short8*)&wl[tid * 8] = *(const short8*)&ws[tid * 8];
    __syncthreads();

    int wid = tid >> 6, lane = tid & 63, c = lane & 15, kg = lane >> 4;
    int t = blockIdx.x * 4 + wid;        // NE/16 tiles, grid exact
    int e0 = t * 16;

    short8 a = (short8)0;
    if (kg < 2) {
        const float* er = ein + (size_t)(e0 + c) * 16 + kg * 8;
        f32x4 u0 = *(const f32x4*)er, u1 = *(const f32x4*)(er + 4);
        #pragma unroll
        for (int j = 0; j < 4; ++j) { a[j] = (short)f2bf(u0[j]); a[4 + j] = (short)f2bf(u1[j]); }
    }
    f32x4 acc[4];
    #pragma unroll
    for (int nt = 0; nt < 4; ++nt) {
        float bv = b[nt * 16 + c];
        acc[nt] = f32x4{bv, bv, bv, bv};
        short8 bf = *(const short8*)&wl[(kg * 64 + nt * 16 + c) * 8];
        acc[nt] = __builtin_amdgcn_mfma_f32_16x16x32_bf16(a, bf, acc[nt], 0, 0, 0);
    }
    #pragma unroll
    for (int nt = 0; nt < 4; ++nt)
        #pragma unroll
        for (int i = 0; i < 4; ++i)
            bbuf[wid][(kg * 4 + i) * 64 + nt * 16 + c] = f2bf(acc[nt][i]);
    #pragma unroll
    for (int r = 0; r < 2; ++r) {
        int q = r * 64 + lane;
        *(short8*)&eb[(size_t)(e0 + (q >> 3)) * 64 + (q & 7) * 8] =
            *(short8*)&bbuf[wid][q * 8];
    }
}

// ---------------------------------------------------------------------------
// msg = relu([x[src]|e] @ [[I],[lw]] + lb); agg[dst] += msg   [MFMA bf16]
// ---------------------------------------------------------------------------
__global__ __launch_bounds__(256) void k_msg_mfma(
    const ushort* __restrict__ xb, const ushort* __restrict__ eb,
    const int* __restrict__ src, const int* __restrict__ dst,
    const ushort* __restrict__ wms, const float* __restrict__ lb,
    float* __restrict__ agg)
{
    __shared__ ushort wl[128 * 64];
    int tid = threadIdx.x;
    #pragma unroll
    for (int i = 0; i < 4; ++i)
        *(short8*)&wl[(i * 256 + tid) * 8] = *(const short8*)&wms[(i * 256 + tid) * 8];
    __syncthreads();

    int wid = tid >> 6, lane = tid & 63;
    int c = lane & 15, kg = lane >> 4;
    float bv[4];
    #pragma unroll
    for (int nt = 0; nt < 4; ++nt) bv[nt] = lb[nt * 16 + c];

    #pragma unroll 1
    for (int t4 = 0; t4 < 4; ++t4) {
        int e0 = blockIdx.x * 256 + wid * 64 + t4 * 16;
        int myedge = e0 + c;
        const ushort* xs = xb + (size_t)src[myedge] * 64;
        const ushort* ee = eb + (size_t)myedge * 64;
        short8 a[4];
        a[0] = *(const short8*)(xs + kg * 8);
        a[1] = *(const short8*)(xs + 32 + kg * 8);
        a[2] = *(const short8*)(ee + kg * 8);
        a[3] = *(const short8*)(ee + 32 + kg * 8);

        f32x4 acc[4];
        #pragma unroll
        for (int nt = 0; nt < 4; ++nt) acc[nt] = f32x4{bv[nt], bv[nt], bv[nt], bv[nt]};
        #pragma unroll
        for (int ks = 0; ks < 4; ++ks) {
            #pragma unroll
            for (int nt = 0; nt < 4; ++nt) {
                short8 bf = *(const short8*)&wl[((ks * 4 + kg) * 64 + nt * 16 + c) * 8];
                acc[nt] = __builtin_amdgcn_mfma_f32_16x16x32_bf16(a[ks], bf, acc[nt], 0, 0, 0);
            }
        }
        int drow[4];
        #pragma unroll
        for (int i = 0; i < 4; ++i) drow[i] = dst[e0 + kg * 4 + i];
        #pragma unroll
        for (int nt = 0; nt < 4; ++nt) {
            #pragma unroll
            for (int i = 0; i < 4; ++i) {
                float m = fmaxf(acc[nt][i], 0.f);
                unsafeAtomicAdd(&agg[(size_t)drow[i] * 64 + nt * 16 + c], m);
            }
        }
    }
}

// ---------------------------------------------------------------------------
// h = relu((x+agg)@w1+b1)@w2+b2  [MFMA bf16], writes h f32 + BN partial sums
// ---------------------------------------------------------------------------
__global__ __launch_bounds__(256) void k_conv_mfma(
    const float* __restrict__ x, float* __restrict__ hio,
    const ushort* __restrict__ w1s, const float* __restrict__ b1,
    const ushort* __restrict__ w2s, const float* __restrict__ b2,
    float* __restrict__ stats)
{
    __shared__ ushort w1l[64 * 64];
    __shared__ ushort w2l[64 * 64];
    __shared__ ushort h1l[4][1024];
    __shared__ float red[2][4][64];
    int tid = threadIdx.x;
    #pragma unroll
    for (int i = 0; i < 2; ++i) {
        *(short8*)&w1l[(i * 256 + tid) * 8] = *(const short8*)&w1s[(i * 256 + tid) * 8];
        *(short8*)&w2l[(i * 256 + tid) * 8] = *(const short8*)&w2s[(i * 256 + tid) * 8];
    }
    __syncthreads();

    int wid = tid >> 6, lane = tid & 63;
    int c = lane & 15, kg = lane >> 4;

    short8 w2f[2][4];
    #pragma unroll
    for (int ks = 0; ks < 2; ++ks)
        #pragma unroll
        for (int nt = 0; nt < 4; ++nt)
            w2f[ks][nt] = *(const short8*)&w2l[((ks * 4 + kg) * 64 + nt * 16 + c) * 8];

    float b1v[4], b2v[4];
    #pragma unroll
    for (int nt = 0; nt < 4; ++nt) { b1v[nt] = b1[nt * 16 + c]; b2v[nt] = b2[nt * 16 + c]; }

    float s1[4] = {0.f, 0.f, 0.f, 0.f}, s2[4] = {0.f, 0.f, 0.f, 0.f};
    ushort* hl = h1l[wid];

    int t = blockIdx.x * 4 + wid;
    if (t < NN / 16) {
        int n0 = t * 16;
        const float* xr = x + (size_t)(n0 + c) * 64;
        const float* hr = hio + (size_t)(n0 + c) * 64;
        short8 a[2];
        #pragma unroll
        for (int ks = 0; ks < 2; ++ks) {
            f32x4 u0 = *(const f32x4*)(xr + ks * 32 + kg * 8);
            f32x4 u1 = *(const f32x4*)(xr + ks * 32 + kg * 8 + 4);
            f32x4 v0 = *(const f32x4*)(hr + ks * 32 + kg * 8);
            f32x4 v1 = *(const f32x4*)(hr + ks * 32 + kg * 8 + 4);
            #pragma unroll
            for (int j = 0; j < 4; ++j) {
                a[ks][j]     = (short)f2bf(u0[j] + v0[j]);
                a[ks][4 + j] = (short)f2bf(u1[j] + v1[j]);
            }
        }
        f32x4 acc[4];
        #pragma unroll
        for (int nt = 0; nt < 4; ++nt) acc[nt] = f32x4{b1v[nt], b1v[nt], b1v[nt], b1v[nt]};
        #pragma unroll
        for (int ks = 0; ks < 2; ++ks) {
            #pragma unroll
            for (int nt = 0; nt < 4; ++nt) {
                short8 bf = *(const short8*)&w1l[((ks * 4 + kg) * 64 + nt * 16 + c) * 8];
                acc[nt] = __builtin_amdgcn_mfma_f32_16x16x32_bf16(a[ks], bf, acc[nt], 0, 0, 0);
            }
        }
        #pragma unroll
        for (int nt = 0; nt < 4; ++nt) {
            #pragma unroll
            for (int i = 0; i < 4; ++i) {
                int rr = kg * 4 + i, cc = nt * 16 + c;
                hl[((cc >> 3) * 16 + rr) * 8 + (cc & 7)] = f2bf(fmaxf(acc[nt][i], 0.f));
            }
        }
        f32x4 acc2[4];
        #pragma unroll
        for (int nt = 0; nt < 4; ++nt) acc2[nt] = f32x4{b2v[nt], b2v[nt], b2v[nt], b2v[nt]};
        #pragma unroll
        for (int ks = 0; ks < 2; ++ks) {
            short8 ha = *(const short8*)&hl[((ks * 4 + kg) * 16 + c) * 8];
            #pragma unroll
            for (int nt = 0; nt < 4; ++nt)
                acc2[nt] = __builtin_amdgcn_mfma_f32_16x16x32_bf16(ha, w2f[ks][nt], acc2[nt], 0, 0, 0);
        }
        #pragma unroll
        for (int nt = 0; nt < 4; ++nt) {
            #pragma unroll
            for (int i = 0; i < 4; ++i) {
                int rr = kg * 4 + i, cc = nt * 16 + c;
                float h2 = acc2[nt][i];
                hio[(size_t)(n0 + rr) * 64 + cc] = h2;
                s1[nt] += h2;
                s2[nt] += h2 * h2;
            }
        }
    }
    #pragma unroll
    for (int nt = 0; nt < 4; ++nt) {
        float v1 = s1[nt], v2 = s2[nt];
        v1 += __shfl_xor(v1, 16); v1 += __shfl_xor(v1, 32);
        v2 += __shfl_xor(v2, 16); v2 += __shfl_xor(v2, 32);
        s1[nt] = v1; s2[nt] = v2;
    }
    if (lane < 16) {
        #pragma unroll
        for (int nt = 0; nt < 4; ++nt) {
            red[0][wid][nt * 16 + c] = s1[nt];
            red[1][wid][nt * 16 + c] = s2[nt];
        }
    }
    __syncthreads();
    if (wid == 0) {
        float a = red[0][0][lane] + red[0][1][lane] + red[0][2][lane] + red[0][3][lane];
        float b = red[1][0][lane] + red[1][1][lane] + red[1][2][lane] + red[1][3][lane];
        unsafeAtomicAdd(&stats[lane], a);
        unsafeAtomicAdd(&stats[64 + lane], b);
    }
}

__global__ void k_bnfin(float* __restrict__ stats,
                        const float* __restrict__ gamma,
                        const float* __restrict__ beta)
{
    int j = threadIdx.x;
    float mu = stats[j] * (1.f / NN);
    float var = stats[64 + j] * (1.f / NN) - mu * mu;
    float a = gamma[j] * rsqrtf(var + 1e-5f);
    stats[128 + j] = a;
    stats[192 + j] = beta[j] - mu * a;
}

// ---------------------------------------------------------------------------
// x = (x + relu(h*a+c))/2 ; bf16 mirror.  4 elems/thread, vectorized.
// ---------------------------------------------------------------------------
__global__ __launch_bounds__(256) void k_xupd4(float* __restrict__ x,
                                               const float* __restrict__ h,
                                               const float* __restrict__ stats,
                                               ushort* __restrict__ xb)
{
    int idx = blockIdx.x * 256 + threadIdx.x;   // NN*16 threads
    int j4 = (idx & 15) * 4;
    f32x4 hv = *(const f32x4*)&h[(size_t)idx * 4];
    f32x4 xv = *(const f32x4*)&x[(size_t)idx * 4];
    f32x4 av = *(const f32x4*)&stats[128 + j4];
    f32x4 cv = *(const f32x4*)&stats[192 + j4];
    f32x4 xo;
    ushort4v bo;
    #pragma unroll
    for (int i = 0; i < 4; ++i) {
        float r = fmaxf(fmaf(hv[i], av[i], cv[i]), 0.f);
        float xn = (xv[i] + r) * 0.5f;
        xo[i] = xn;
        bo[i] = f2bf(xn);
    }
    *(f32x4*)&x[(size_t)idx * 4] = xo;
    *(ushort4v*)&xb[(size_t)idx * 4] = bo;
}

// ---------------------------------------------------------------------------
// e += 0.5*( relu(cat(x[s],x[d],e)@w1+b1) @ w2 + b2 )   [MFMA bf16]
// ---------------------------------------------------------------------------
__global__ __launch_bounds__(256) void k_emlp_mfma(
    const ushort* __restrict__ xb, ushort* __restrict__ eb,
    const int* __restrict__ src, const int* __restrict__ dst,
    const ushort* __restrict__ w1s, const float* __restrict__ b1,
    const ushort* __restrict__ w2s, const float* __restrict__ b2)
{
    __shared__ ushort w1l[192 * 64];
    __shared__ ushort w2l[64 * 64];
    __shared__ ushort h1l[4][1024];
    int tid = threadIdx.x;
    #pragma unroll
    for (int i = 0; i < 6; ++i)
        *(short8*)&w1l[(i * 256 + tid) * 8] = *(const short8*)&w1s[(i * 256 + tid) * 8];
    #pragma unroll
    for (int i = 0; i < 2; ++i)
        *(short8*)&w2l[(i * 256 + tid) * 8] = *(const short8*)&w2s[(i * 256 + tid) * 8];
    __syncthreads();

    int wid = tid >> 6, lane = tid & 63;
    int c = lane & 15, kg = lane >> 4;

    short8 w2f[2][4];
    #pragma unroll
    for (int ks = 0; ks < 2; ++ks)
        #pragma unroll
        for (int nt = 0; nt < 4; ++nt)
            w2f[ks][nt] = *(const short8*)&w2l[((ks * 4 + kg) * 64 + nt * 16 + c) * 8];

    float b1v[4], b2v[4];
    #pragma unroll
    for (int nt = 0; nt < 4; ++nt) { b1v[nt] = b1[nt * 16 + c]; b2v[nt] = b2[nt * 16 + c]; }

    ushort* hl = h1l[wid];

    #pragma unroll 1
    for (int t4 = 0; t4 < 4; ++t4) {
        int e0 = blockIdx.x * 256 + wid * 64 + t4 * 16;
        int myedge = e0 + c;
        int s = src[myedge], d = dst[myedge];
        const ushort* xs = xb + (size_t)s * 64;
        const ushort* xd = xb + (size_t)d * 64;
        const ushort* ee = eb + (size_t)myedge * 64;
        short8 a[6];
        a[0] = *(const short8*)(xs + kg * 8);
        a[1] = *(const short8*)(xs + 32 + kg * 8);
        a[2] = *(const short8*)(xd + kg * 8);
        a[3] = *(const short8*)(xd + 32 + kg * 8);
        a[4] = *(const short8*)(ee + kg * 8);
        a[5] = *(const short8*)(ee + 32 + kg * 8);

        f32x4 acc[4];
        #pragma unroll
        for (int nt = 0; nt < 4; ++nt) acc[nt] = f32x4{b1v[nt], b1v[nt], b1v[nt], b1v[nt]};
        #pragma unroll
        for (int ks = 0; ks < 6; ++ks) {
            #pragma unroll
            for (int nt = 0; nt < 4; ++nt) {
                short8 bf = *(const short8*)&w1l[((ks * 4 + kg) * 64 + nt * 16 + c) * 8];
                acc[nt] = __builtin_amdgcn_mfma_f32_16x16x32_bf16(a[ks], bf, acc[nt], 0, 0, 0);
            }
        }
        #pragma unroll
        for (int nt = 0; nt < 4; ++nt) {
            #pragma unroll
            for (int i = 0; i < 4; ++i) {
                int rr = kg * 4 + i, cc = nt * 16 + c;
                hl[((cc >> 3) * 16 + rr) * 8 + (cc & 7)] = f2bf(fmaxf(acc[nt][i], 0.f));
            }
        }
        f32x4 acc2[4];
        #pragma unroll
        for (int nt = 0; nt < 4; ++nt) acc2[nt] = f32x4{b2v[nt], b2v[nt], b2v[nt], b2v[nt]};
        #pragma unroll
        for (int ks = 0; ks < 2; ++ks) {
            short8 ha = *(const short8*)&hl[((ks * 4 + kg) * 16 + c) * 8];
            #pragma unroll
            for (int nt = 0; nt < 4; ++nt)
                acc2[nt] = __builtin_amdgcn_mfma_f32_16x16x32_bf16(ha, w2f[ks][nt], acc2[nt], 0, 0, 0);
        }
        #pragma unroll
        for (int nt = 0; nt < 4; ++nt) {
            #pragma unroll
            for (int i = 0; i < 4; ++i) {
                int rr = kg * 4 + i, cc = nt * 16 + c;
                size_t off = (size_t)(e0 + rr) * 64 + cc;
                eb[off] = f2bf(bf2f(eb[off]) + 0.5f * acc2[nt][i]);
            }
        }
    }
}

// ---------------------------------------------------------------------------
// readout
// ---------------------------------------------------------------------------
__global__ __launch_bounds__(256) void k_readout_mfma(
    const ushort* __restrict__ xb, const ushort* __restrict__ eb,
    const int* __restrict__ src, const int* __restrict__ dst,
    const ushort* __restrict__ w1s, const float* __restrict__ b1,
    const float* __restrict__ w2, const float* __restrict__ b2,
    const float* __restrict__ w3, const float* __restrict__ b3,
    float* __restrict__ logit)
{
    __shared__ ushort w1l[192 * 64];
    __shared__ ushort hw[4][64 * 50];
    int tid = threadIdx.x;
    #pragma unroll
    for (int i = 0; i < 6; ++i)
        *(short8*)&w1l[(i * 256 + tid) * 8] = *(const short8*)&w1s[(i * 256 + tid) * 8];
    __syncthreads();

    int wid = tid >> 6, lane = tid & 63;
    int c = lane & 15, kg = lane >> 4;
    float b1v[4];
    #pragma unroll
    for (int nt = 0; nt < 4; ++nt) b1v[nt] = (nt * 16 + c < 50) ? b1[nt * 16 + c] : 0.f;

    #pragma unroll 1
    for (int t4 = 0; t4 < 4; ++t4) {
        int e0 = blockIdx.x * 256 + wid * 64 + t4 * 16;
        int myedge = e0 + c;
        int s = src[myedge], d = dst[myedge];
        const ushort* xs = xb + (size_t)s * 64;
        const ushort* xd = xb + (size_t)d * 64;
        const ushort* ee = eb + (size_t)myedge * 64;
        short8 a[6];
        a[0] = brelu(*(const short8*)(xs + kg * 8));
        a[1] = brelu(*(const short8*)(xs + 32 + kg * 8));
        a[2] = brelu(*(const short8*)(xd + kg * 8));
        a[3] = brelu(*(const short8*)(xd + 32 + kg * 8));
        a[4] = *(const short8*)(ee + kg * 8);
        a[5] = *(const short8*)(ee + 32 + kg * 8);

        f32x4 acc[4];
        #pragma unroll
        for (int nt = 0; nt < 4; ++nt) acc[nt] = f32x4{b1v[nt], b1v[nt], b1v[nt], b1v[nt]};
        #pragma unroll
        for (int ks = 0; ks < 6; ++ks) {
            #pragma unroll
            for (int nt = 0; nt < 4; ++nt) {
                short8 bf = *(const short8*)&w1l[((ks * 4 + kg) * 64 + nt * 16 + c) * 8];
                acc[nt] = __builtin_amdgcn_mfma_f32_16x16x32_bf16(a[ks], bf, acc[nt], 0, 0, 0);
            }
        }
        #pragma unroll
        for (int nt = 0; nt < 4; ++nt) {
            #pragma unroll
            for (int i = 0; i < 4; ++i) {
                int rr = kg * 4 + i, cc = nt * 16 + c;
                if (cc < 50)
                    hw[wid][(t4 * 16 + rr) * 50 + cc] = f2bf(fmaxf(acc[nt][i], 0.f));
            }
        }
    }
    int edge = blockIdx.x * 256 + wid * 64 + lane;
    const ushort* hrow = &hw[wid][lane * 50];
    float a25[25];
    #pragma unroll
    for (int j = 0; j < 25; ++j) a25[j] = b2[j];
    #pragma unroll 2
    for (int k = 0; k < 50; ++k) {
        float hv = bf2f(hrow[k]);
        #pragma unroll
        for (int j = 0; j < 25; ++j) a25[j] = fmaf(hv, w2[k * 25 + j], a25[j]);
    }
    float lg = b3[0];
    #pragma unroll
    for (int k = 0; k < 25; ++k) lg = fmaf(fmaxf(a25[k], 0.f), w3[k], lg);
    logit[edge] = lg;
}

// ---------------------------------------------------------------------------
extern "C" void kernel_launch(void* const* d_in, const int* in_sizes, int n_in,
                              void* d_out, int out_size, void* d_ws, size_t ws_size,
                              hipStream_t stream)
{
    const float* x_in  = (const float*)d_in[0];
    const float* eattr = (const float*)d_in[1];
    const int*   src   = (const int*)d_in[2];
    const int*   dst   = (const int*)d_in[3];
    const float* n_w   = (const float*)d_in[4];
    const float* n_b   = (const float*)d_in[5];
    const float* e_w   = (const float*)d_in[6];
    const float* e_b   = (const float*)d_in[7];
    const float* lw    = (const float*)d_in[8];
    const float* lb    = (const float*)d_in[9];
    const float* cw1   = (const float*)d_in[10];
    const float* cb1   = (const float*)d_in[11];
    const float* cw2   = (const float*)d_in[12];
    const float* cb2   = (const float*)d_in[13];
    const float* ew1   = (const float*)d_in[14];
    const float* eb1   = (const float*)d_in[15];
    const float* ew2   = (const float*)d_in[16];
    const float* eb2   = (const float*)d_in[17];
    const float* gam   = (const float*)d_in[18];
    const float* bet   = (const float*)d_in[19];
    const float* m1w   = (const float*)d_in[20];
    const float* m1b   = (const float*)d_in[21];
    const float* m2w   = (const float*)d_in[22];
    const float* m2b   = (const float*)d_in[23];
    const float* m3w   = (const float*)d_in[24];
    const float* m3b   = (const float*)d_in[25];

    float* xbuf  = (float*)d_out;                  // [NN,64] f32 master (output 0)
    float* logit = xbuf + (size_t)NN * 64;         // [NE]

    ushort* eb    = (ushort*)d_ws;                 // [NE,64] bf16 e master
    float*  tmp   = (float*)(eb + (size_t)NE * 64);// [NN,64] agg -> h
    float*  stats = tmp + (size_t)NN * 64;         // 256
    ushort* w1s   = (ushort*)(stats + 256);        // 2*192*64
    ushort* w2s   = w1s + 2 * 192 * 64;            // 2*64*64
    ushort* m1s   = w2s + 2 * 64 * 64;             // 192*64
    ushort* xb    = m1s + 192 * 64;                // [NN,64] bf16 mirror of x
    ushort* wms   = xb + (size_t)NN * 64;          // 2*128*64 msg weights
    ushort* cw1s  = wms + 2 * 128 * 64;            // 2*64*64
    ushort* cw2s  = cw1s + 2 * 64 * 64;            // 2*64*64
    ushort* nws   = cw2s + 2 * 64 * 64;            // 32*64 node emb
    ushort* ews   = nws + 32 * 64;                 // 32*64 edge emb (K-padded)

    // weight prep (bf16 + subtile)
    k_w_subtile<<<48, 256, 0, stream>>>(ew1,            w1s,            192, 64);
    k_w_subtile<<<48, 256, 0, stream>>>(ew1 + 192 * 64, w1s + 192 * 64, 192, 64);
    k_w_subtile<<<16, 256, 0, stream>>>(ew2,            w2s,            64, 64);
    k_w_subtile<<<16, 256, 0, stream>>>(ew2 + 64 * 64,  w2s + 64 * 64,  64, 64);
    k_w_subtile<<<48, 256, 0, stream>>>(m1w,            m1s,            192, 50);
    k_w_msg<<<32, 256, 0, stream>>>(lw,           wms);
    k_w_msg<<<32, 256, 0, stream>>>(lw + 64 * 64, wms + 128 * 64);
    k_w_subtile<<<16, 256, 0, stream>>>(cw1,            cw1s,           64, 64);
    k_w_subtile<<<16, 256, 0, stream>>>(cw1 + 64 * 64,  cw1s + 64 * 64, 64, 64);
    k_w_subtile<<<16, 256, 0, stream>>>(cw2,            cw2s,           64, 64);
    k_w_subtile<<<16, 256, 0, stream>>>(cw2 + 64 * 64,  cw2s + 64 * 64, 64, 64);
    k_w_padk<<<8, 256, 0, stream>>>(n_w, nws, 32, 32);
    k_w_padk<<<8, 256, 0, stream>>>(e_w, ews, 16, 32);

    k_node_emb_mfma<<<(NN / 16 + 3) / 4, 256, 0, stream>>>(x_in, nws, n_b, xbuf, xb);
    k_edge_emb_mfma<<<NE / 64, 256, 0, stream>>>(eattr, ews, e_b, eb);

    for (int l = 0; l < 2; ++l) {
        hipMemsetAsync(tmp, 0, (size_t)NN * 64 * sizeof(float), stream);
        hipMemsetAsync(stats, 0, 256 * sizeof(float), stream);
        k_msg_mfma<<<NE / 256, 256, 0, stream>>>(xb, eb, src, dst,
                                                 wms + l * 128 * 64, lb + l * 64, tmp);
        k_conv_mfma<<<(NN / 16 + 3) / 4, 256, 0, stream>>>(
            xbuf, tmp, cw1s + l * 64 * 64, cb1 + l * 64,
            cw2s + l * 64 * 64, cb2 + l * 64, stats);
        k_bnfin<<<1, 64, 0, stream>>>(stats, gam + l * 64, bet + l * 64);
        k_xupd4<<<NN * 16 / 256, 256, 0, stream>>>(xbuf, tmp, stats, xb);
        k_emlp_mfma<<<NE / 256, 256, 0, stream>>>(xb, eb, src, dst,
                                                  w1s + l * 192 * 64, eb1 + l * 64,
                                                  w2s + l * 64 * 64, eb2 + l * 64);
    }

    k_readout_mfma<<<NE / 256, 256, 0, stream>>>(xb, eb, src, dst,
                                                 m1s, m1b, m2w, m2b, m3w, m3b, logit);
}

// Round 5
// 578.232 us; speedup vs baseline: 3.4899x; 1.1397x over previous
//
#include <hip/hip_runtime.h>

#define NN 100000
#define NE 640000
#define NB_SCAN 98   // ceil(NN/1024)

typedef __attribute__((ext_vector_type(8))) short short8;
typedef __attribute__((ext_vector_type(4))) float f32x4;
typedef __attribute__((ext_vector_type(4))) ushort ushort4v;

__device__ __forceinline__ float bf2f(ushort u) {
    unsigned v = ((unsigned)u) << 16;
    return __builtin_bit_cast(float, v);
}
__device__ __forceinline__ ushort f2bf(float f) {
    unsigned u = __builtin_bit_cast(unsigned, f);
    u += 0x7fffu + ((u >> 16) & 1u);   // RNE
    return (ushort)(u >> 16);
}
__device__ __forceinline__ short8 brelu(short8 v) {
    #pragma unroll
    for (int i = 0; i < 8; ++i) v[i] = (v[i] < (short)0) ? (short)0 : v[i];
    return v;
}

// ======================= CSR build (topology, once per call) ================
__global__ void k_hist(const int* __restrict__ dst, int* __restrict__ hist)
{
    int i = blockIdx.x * 256 + threadIdx.x;   // NE threads
    atomicAdd(&hist[dst[i]], 1);
}

// exclusive scan of 1024-elem chunk; writes chunk-local scan + chunk total
__global__ __launch_bounds__(256) void k_scan_part(const int* __restrict__ hist,
                                                   int* __restrict__ rp,
                                                   int* __restrict__ parts)
{
    __shared__ int s[256];
    int b = blockIdx.x, t = threadIdx.x;
    int base = b * 1024 + t * 4;
    int v[4]; int sum = 0;
    #pragma unroll
    for (int i = 0; i < 4; ++i) { int idx = base + i; v[i] = (idx < NN) ? hist[idx] : 0; sum += v[i]; }
    s[t] = sum; __syncthreads();
    for (int off = 1; off < 256; off <<= 1) {
        int x = (t >= off) ? s[t - off] : 0;
        __syncthreads(); s[t] += x; __syncthreads();
    }
    int excl = s[t] - sum;
    if (t == 255) parts[b] = s[255];
    int run = excl;
    #pragma unroll
    for (int i = 0; i < 4; ++i) { int idx = base + i; if (idx < NN) rp[idx] = run; run += v[i]; }
}

__global__ void k_scan_tops(int* __restrict__ parts, int* __restrict__ rp)
{
    __shared__ int s[128];
    int t = threadIdx.x;   // 128 threads
    int v = (t < NB_SCAN) ? parts[t] : 0;
    s[t] = v; __syncthreads();
    for (int off = 1; off < 128; off <<= 1) {
        int x = (t >= off) ? s[t - off] : 0;
        __syncthreads(); s[t] += x; __syncthreads();
    }
    parts[t] = s[t] - v;   // exclusive
    if (t == 0) rp[NN] = NE;
}

__global__ __launch_bounds__(256) void k_scan_add(int* __restrict__ rp,
                                                  const int* __restrict__ parts,
                                                  int* __restrict__ cursor)
{
    int i = blockIdx.x * 256 + threadIdx.x;
    if (i >= NN) return;
    int v = rp[i] + parts[i >> 10];
    rp[i] = v; cursor[i] = v;
}

__global__ void k_scatter(const int* __restrict__ src, const int* __restrict__ dst,
                          int* __restrict__ cursor, int* __restrict__ eidx,
                          int* __restrict__ ssrc)
{
    int i = blockIdx.x * 256 + threadIdx.x;   // NE threads
    int d = dst[i];
    int p = atomicAdd(&cursor[d], 1);
    eidx[p] = i; ssrc[p] = src[i];
}

// ======================= weight prep =======================================
__global__ void k_w_subtile(const float* __restrict__ w, ushort* __restrict__ out,
                            int K, int Nin)
{
    int t = blockIdx.x * 256 + threadIdx.x;
    if (t >= K * 64) return;
    int k = t >> 6, c = t & 63;
    float v = (c < Nin) ? w[k * Nin + c] : 0.f;
    out[((k >> 3) * 64 + c) * 8 + (k & 7)] = f2bf(v);
}

__global__ void k_w_padk(const float* __restrict__ w, ushort* __restrict__ out,
                         int Kreal, int Kpad)
{
    int t = blockIdx.x * 256 + threadIdx.x;
    if (t >= Kpad * 64) return;
    int k = t >> 6, c = t & 63;
    float v = (k < Kreal) ? w[k * 64 + c] : 0.f;
    out[((k >> 3) * 64 + c) * 8 + (k & 7)] = f2bf(v);
}

__global__ void k_w_msg(const float* __restrict__ lw, ushort* __restrict__ out)
{
    int t = blockIdx.x * 256 + threadIdx.x;   // 128*64
    if (t >= 128 * 64) return;
    int k = t >> 6, c = t & 63;
    float v = (k < 64) ? (k == c ? 1.f : 0.f) : lw[(k - 64) * 64 + c];
    out[((k >> 3) * 64 + c) * 8 + (k & 7)] = f2bf(v);
}

// ======================= embeddings ========================================
__global__ __launch_bounds__(256) void k_node_emb_mfma(
    const float* __restrict__ xin, const ushort* __restrict__ ws,
    const float* __restrict__ b, float* __restrict__ xout,
    ushort* __restrict__ xb)
{
    __shared__ ushort wl[32 * 64];
    __shared__ float fbuf[4][16 * 64];
    __shared__ ushort bbuf[4][16 * 64];
    int tid = threadIdx.x;
    *(short8*)&wl[tid * 8] = *(const short8*)&ws[tid * 8];
    __syncthreads();

    int wid = tid >> 6, lane = tid & 63, c = lane & 15, kg = lane >> 4;
    int t = blockIdx.x * 4 + wid;
    if (t >= NN / 16) return;
    int n0 = t * 16;

    const float* xr = xin + (size_t)(n0 + c) * 32 + kg * 8;
    f32x4 u0 = *(const f32x4*)xr, u1 = *(const f32x4*)(xr + 4);
    short8 a;
    #pragma unroll
    for (int j = 0; j < 4; ++j) { a[j] = (short)f2bf(u0[j]); a[4 + j] = (short)f2bf(u1[j]); }

    f32x4 acc[4];
    #pragma unroll
    for (int nt = 0; nt < 4; ++nt) {
        float bv = b[nt * 16 + c];
        acc[nt] = f32x4{bv, bv, bv, bv};
        short8 bf = *(const short8*)&wl[(kg * 64 + nt * 16 + c) * 8];
        acc[nt] = __builtin_amdgcn_mfma_f32_16x16x32_bf16(a, bf, acc[nt], 0, 0, 0);
    }
    #pragma unroll
    for (int nt = 0; nt < 4; ++nt)
        #pragma unroll
        for (int i = 0; i < 4; ++i) {
            int rr = kg * 4 + i, cc = nt * 16 + c;
            float v = acc[nt][i];
            fbuf[wid][rr * 64 + cc] = v;
            bbuf[wid][rr * 64 + cc] = f2bf(v);
        }
    #pragma unroll
    for (int r = 0; r < 4; ++r) {
        int q = r * 64 + lane;
        *(f32x4*)&xout[(size_t)(n0 + (q >> 4)) * 64 + (q & 15) * 4] =
            *(f32x4*)&fbuf[wid][q * 4];
    }
    #pragma unroll
    for (int r = 0; r < 2; ++r) {
        int q = r * 64 + lane;
        *(short8*)&xb[(size_t)(n0 + (q >> 3)) * 64 + (q & 7) * 8] =
            *(short8*)&bbuf[wid][q * 8];
    }
}

__global__ __launch_bounds__(256) void k_edge_emb_mfma(
    const float* __restrict__ ein, const ushort* __restrict__ ws,
    const float* __restrict__ b, ushort* __restrict__ eb)
{
    __shared__ ushort wl[32 * 64];
    __shared__ ushort bbuf[4][16 * 64];
    int tid = threadIdx.x;
    *(short8*)&wl[tid * 8] = *(const short8*)&ws[tid * 8];
    __syncthreads();

    int wid = tid >> 6, lane = tid & 63, c = lane & 15, kg = lane >> 4;
    int t = blockIdx.x * 4 + wid;
    int e0 = t * 16;

    short8 a = (short8)0;
    if (kg < 2) {
        const float* er = ein + (size_t)(e0 + c) * 16 + kg * 8;
        f32x4 u0 = *(const f32x4*)er, u1 = *(const f32x4*)(er + 4);
        #pragma unroll
        for (int j = 0; j < 4; ++j) { a[j] = (short)f2bf(u0[j]); a[4 + j] = (short)f2bf(u1[j]); }
    }
    f32x4 acc[4];
    #pragma unroll
    for (int nt = 0; nt < 4; ++nt) {
        float bv = b[nt * 16 + c];
        acc[nt] = f32x4{bv, bv, bv, bv};
        short8 bf = *(const short8*)&wl[(kg * 64 + nt * 16 + c) * 8];
        acc[nt] = __builtin_amdgcn_mfma_f32_16x16x32_bf16(a, bf, acc[nt], 0, 0, 0);
    }
    #pragma unroll
    for (int nt = 0; nt < 4; ++nt)
        #pragma unroll
        for (int i = 0; i < 4; ++i)
            bbuf[wid][(kg * 4 + i) * 64 + nt * 16 + c] = f2bf(acc[nt][i]);
    #pragma unroll
    for (int r = 0; r < 2; ++r) {
        int q = r * 64 + lane;
        *(short8*)&eb[(size_t)(e0 + (q >> 3)) * 64 + (q & 7) * 8] =
            *(short8*)&bbuf[wid][q * 8];
    }
}

// ======================= msg stage A (sorted order, no atomics) =============
// msgbuf[p] = relu([x[ssrc[p]] | e[eidx[p]]] @ [[I],[lw]] + lb)   bf16
__global__ __launch_bounds__(256) void k_msgA(
    const ushort* __restrict__ xb, const ushort* __restrict__ eb,
    const int* __restrict__ eidx, const int* __restrict__ ssrc,
    const ushort* __restrict__ wms, const float* __restrict__ lb,
    ushort* __restrict__ msgbuf)
{
    __shared__ ushort wl[128 * 64];
    __shared__ ushort bbuf[4][16 * 64];
    int tid = threadIdx.x;
    #pragma unroll
    for (int i = 0; i < 4; ++i)
        *(short8*)&wl[(i * 256 + tid) * 8] = *(const short8*)&wms[(i * 256 + tid) * 8];
    __syncthreads();

    int wid = tid >> 6, lane = tid & 63;
    int c = lane & 15, kg = lane >> 4;
    float bv[4];
    #pragma unroll
    for (int nt = 0; nt < 4; ++nt) bv[nt] = lb[nt * 16 + c];

    #pragma unroll 1
    for (int t4 = 0; t4 < 4; ++t4) {
        int p0 = blockIdx.x * 256 + wid * 64 + t4 * 16;
        int row = p0 + c;
        int edge = eidx[row], s = ssrc[row];
        const ushort* xs = xb + (size_t)s * 64;
        const ushort* ee = eb + (size_t)edge * 64;
        short8 a[4];
        a[0] = *(const short8*)(xs + kg * 8);
        a[1] = *(const short8*)(xs + 32 + kg * 8);
        a[2] = *(const short8*)(ee + kg * 8);
        a[3] = *(const short8*)(ee + 32 + kg * 8);

        f32x4 acc[4];
        #pragma unroll
        for (int nt = 0; nt < 4; ++nt) acc[nt] = f32x4{bv[nt], bv[nt], bv[nt], bv[nt]};
        #pragma unroll
        for (int ks = 0; ks < 4; ++ks) {
            #pragma unroll
            for (int nt = 0; nt < 4; ++nt) {
                short8 bf = *(const short8*)&wl[((ks * 4 + kg) * 64 + nt * 16 + c) * 8];
                acc[nt] = __builtin_amdgcn_mfma_f32_16x16x32_bf16(a[ks], bf, acc[nt], 0, 0, 0);
            }
        }
        #pragma unroll
        for (int nt = 0; nt < 4; ++nt)
            #pragma unroll
            for (int i = 0; i < 4; ++i)
                bbuf[wid][(kg * 4 + i) * 64 + nt * 16 + c] = f2bf(fmaxf(acc[nt][i], 0.f));
        #pragma unroll
        for (int r = 0; r < 2; ++r) {
            int q = r * 64 + lane;
            *(short8*)&msgbuf[(size_t)(p0 + (q >> 3)) * 64 + (q & 7) * 8] =
                *(short8*)&bbuf[wid][q * 8];
        }
    }
}

// ======================= conv with CSR aggregation ==========================
// hp = x + sum_{j in [rp[n],rp[n+1])} msgbuf[j];  h = relu(hp@w1+b1)@w2+b2
__global__ __launch_bounds__(256) void k_conv_csr(
    const float* __restrict__ x, const ushort* __restrict__ msgbuf,
    const int* __restrict__ rp, float* __restrict__ hout,
    const ushort* __restrict__ w1s, const float* __restrict__ b1,
    const ushort* __restrict__ w2s, const float* __restrict__ b2,
    float* __restrict__ stats)
{
    __shared__ ushort w1l[64 * 64];
    __shared__ ushort w2l[64 * 64];
    __shared__ ushort h1l[4][1024];
    __shared__ float red[2][4][64];
    int tid = threadIdx.x;
    #pragma unroll
    for (int i = 0; i < 2; ++i) {
        *(short8*)&w1l[(i * 256 + tid) * 8] = *(const short8*)&w1s[(i * 256 + tid) * 8];
        *(short8*)&w2l[(i * 256 + tid) * 8] = *(const short8*)&w2s[(i * 256 + tid) * 8];
    }
    __syncthreads();

    int wid = tid >> 6, lane = tid & 63;
    int c = lane & 15, kg = lane >> 4;

    short8 w2f[2][4];
    #pragma unroll
    for (int ks = 0; ks < 2; ++ks)
        #pragma unroll
        for (int nt = 0; nt < 4; ++nt)
            w2f[ks][nt] = *(const short8*)&w2l[((ks * 4 + kg) * 64 + nt * 16 + c) * 8];

    float b1v[4], b2v[4];
    #pragma unroll
    for (int nt = 0; nt < 4; ++nt) { b1v[nt] = b1[nt * 16 + c]; b2v[nt] = b2[nt * 16 + c]; }

    float s1[4] = {0.f, 0.f, 0.f, 0.f}, s2[4] = {0.f, 0.f, 0.f, 0.f};
    ushort* hl = h1l[wid];

    int t = blockIdx.x * 4 + wid;
    if (t < NN / 16) {
        int n0 = t * 16;
        int n = n0 + c;
        int jb = rp[n], je = rp[n + 1];
        float sm0[8] = {0,0,0,0,0,0,0,0}, sm1[8] = {0,0,0,0,0,0,0,0};
        for (int j = jb; j < je; ++j) {
            short8 m0 = *(const short8*)&msgbuf[(size_t)j * 64 + kg * 8];
            short8 m1 = *(const short8*)&msgbuf[(size_t)j * 64 + 32 + kg * 8];
            #pragma unroll
            for (int i = 0; i < 8; ++i) {
                sm0[i] += bf2f((ushort)m0[i]);
                sm1[i] += bf2f((ushort)m1[i]);
            }
        }
        const float* xr = x + (size_t)n * 64;
        f32x4 u0 = *(const f32x4*)(xr + kg * 8);
        f32x4 u1 = *(const f32x4*)(xr + kg * 8 + 4);
        f32x4 v0 = *(const f32x4*)(xr + 32 + kg * 8);
        f32x4 v1 = *(const f32x4*)(xr + 32 + kg * 8 + 4);
        short8 a[2];
        #pragma unroll
        for (int j = 0; j < 4; ++j) {
            a[0][j]     = (short)f2bf(u0[j] + sm0[j]);
            a[0][4 + j] = (short)f2bf(u1[j] + sm0[4 + j]);
            a[1][j]     = (short)f2bf(v0[j] + sm1[j]);
            a[1][4 + j] = (short)f2bf(v1[j] + sm1[4 + j]);
        }
        f32x4 acc[4];
        #pragma unroll
        for (int nt = 0; nt < 4; ++nt) acc[nt] = f32x4{b1v[nt], b1v[nt], b1v[nt], b1v[nt]};
        #pragma unroll
        for (int ks = 0; ks < 2; ++ks) {
            #pragma unroll
            for (int nt = 0; nt < 4; ++nt) {
                short8 bf = *(const short8*)&w1l[((ks * 4 + kg) * 64 + nt * 16 + c) * 8];
                acc[nt] = __builtin_amdgcn_mfma_f32_16x16x32_bf16(a[ks], bf, acc[nt], 0, 0, 0);
            }
        }
        #pragma unroll
        for (int nt = 0; nt < 4; ++nt) {
            #pragma unroll
            for (int i = 0; i < 4; ++i) {
                int rr = kg * 4 + i, cc = nt * 16 + c;
                hl[((cc >> 3) * 16 + rr) * 8 + (cc & 7)] = f2bf(fmaxf(acc[nt][i], 0.f));
            }
        }
        f32x4 acc2[4];
        #pragma unroll
        for (int nt = 0; nt < 4; ++nt) acc2[nt] = f32x4{b2v[nt], b2v[nt], b2v[nt], b2v[nt]};
        #pragma unroll
        for (int ks = 0; ks < 2; ++ks) {
            short8 ha = *(const short8*)&hl[((ks * 4 + kg) * 16 + c) * 8];
            #pragma unroll
            for (int nt = 0; nt < 4; ++nt)
                acc2[nt] = __builtin_amdgcn_mfma_f32_16x16x32_bf16(ha, w2f[ks][nt], acc2[nt], 0, 0, 0);
        }
        #pragma unroll
        for (int nt = 0; nt < 4; ++nt) {
            #pragma unroll
            for (int i = 0; i < 4; ++i) {
                int rr = kg * 4 + i, cc = nt * 16 + c;
                float h2 = acc2[nt][i];
                hout[(size_t)(n0 + rr) * 64 + cc] = h2;
                s1[nt] += h2;
                s2[nt] += h2 * h2;
            }
        }
    }
    #pragma unroll
    for (int nt = 0; nt < 4; ++nt) {
        float v1 = s1[nt], v2 = s2[nt];
        v1 += __shfl_xor(v1, 16); v1 += __shfl_xor(v1, 32);
        v2 += __shfl_xor(v2, 16); v2 += __shfl_xor(v2, 32);
        s1[nt] = v1; s2[nt] = v2;
    }
    if (lane < 16) {
        #pragma unroll
        for (int nt = 0; nt < 4; ++nt) {
            red[0][wid][nt * 16 + c] = s1[nt];
            red[1][wid][nt * 16 + c] = s2[nt];
        }
    }
    __syncthreads();
    if (wid == 0) {
        float a = red[0][0][lane] + red[0][1][lane] + red[0][2][lane] + red[0][3][lane];
        float b = red[1][0][lane] + red[1][1][lane] + red[1][2][lane] + red[1][3][lane];
        unsafeAtomicAdd(&stats[lane], a);
        unsafeAtomicAdd(&stats[64 + lane], b);
    }
}

__global__ void k_bnfin(float* __restrict__ stats,
                        const float* __restrict__ gamma,
                        const float* __restrict__ beta)
{
    int j = threadIdx.x;
    float mu = stats[j] * (1.f / NN);
    float var = stats[64 + j] * (1.f / NN) - mu * mu;
    float a = gamma[j] * rsqrtf(var + 1e-5f);
    stats[128 + j] = a;
    stats[192 + j] = beta[j] - mu * a;
}

__global__ __launch_bounds__(256) void k_xupd4(float* __restrict__ x,
                                               const float* __restrict__ h,
                                               const float* __restrict__ stats,
                                               ushort* __restrict__ xb)
{
    int idx = blockIdx.x * 256 + threadIdx.x;   // NN*16 threads
    int j4 = (idx & 15) * 4;
    f32x4 hv = *(const f32x4*)&h[(size_t)idx * 4];
    f32x4 xv = *(const f32x4*)&x[(size_t)idx * 4];
    f32x4 av = *(const f32x4*)&stats[128 + j4];
    f32x4 cv = *(const f32x4*)&stats[192 + j4];
    f32x4 xo;
    ushort4v bo;
    #pragma unroll
    for (int i = 0; i < 4; ++i) {
        float r = fmaxf(fmaf(hv[i], av[i], cv[i]), 0.f);
        float xn = (xv[i] + r) * 0.5f;
        xo[i] = xn;
        bo[i] = f2bf(xn);
    }
    *(f32x4*)&x[(size_t)idx * 4] = xo;
    *(ushort4v*)&xb[(size_t)idx * 4] = bo;
}

// ======================= edge MLP ==========================================
__global__ __launch_bounds__(256) void k_emlp_mfma(
    const ushort* __restrict__ xb, ushort* __restrict__ eb,
    const int* __restrict__ src, const int* __restrict__ dst,
    const ushort* __restrict__ w1s, const float* __restrict__ b1,
    const ushort* __restrict__ w2s, const float* __restrict__ b2)
{
    __shared__ ushort w1l[192 * 64];
    __shared__ ushort w2l[64 * 64];
    __shared__ ushort h1l[4][1024];
    int tid = threadIdx.x;
    #pragma unroll
    for (int i = 0; i < 6; ++i)
        *(short8*)&w1l[(i * 256 + tid) * 8] = *(const short8*)&w1s[(i * 256 + tid) * 8];
    #pragma unroll
    for (int i = 0; i < 2; ++i)
        *(short8*)&w2l[(i * 256 + tid) * 8] = *(const short8*)&w2s[(i * 256 + tid) * 8];
    __syncthreads();

    int wid = tid >> 6, lane = tid & 63;
    int c = lane & 15, kg = lane >> 4;

    short8 w2f[2][4];
    #pragma unroll
    for (int ks = 0; ks < 2; ++ks)
        #pragma unroll
        for (int nt = 0; nt < 4; ++nt)
            w2f[ks][nt] = *(const short8*)&w2l[((ks * 4 + kg) * 64 + nt * 16 + c) * 8];

    float b1v[4], b2v[4];
    #pragma unroll
    for (int nt = 0; nt < 4; ++nt) { b1v[nt] = b1[nt * 16 + c]; b2v[nt] = b2[nt * 16 + c]; }

    ushort* hl = h1l[wid];

    #pragma unroll 1
    for (int t4 = 0; t4 < 4; ++t4) {
        int e0 = blockIdx.x * 256 + wid * 64 + t4 * 16;
        int myedge = e0 + c;
        int s = src[myedge], d = dst[myedge];
        const ushort* xs = xb + (size_t)s * 64;
        const ushort* xd = xb + (size_t)d * 64;
        const ushort* ee = eb + (size_t)myedge * 64;
        short8 a[6];
        a[0] = *(const short8*)(xs + kg * 8);
        a[1] = *(const short8*)(xs + 32 + kg * 8);
        a[2] = *(const short8*)(xd + kg * 8);
        a[3] = *(const short8*)(xd + 32 + kg * 8);
        a[4] = *(const short8*)(ee + kg * 8);
        a[5] = *(const short8*)(ee + 32 + kg * 8);

        f32x4 acc[4];
        #pragma unroll
        for (int nt = 0; nt < 4; ++nt) acc[nt] = f32x4{b1v[nt], b1v[nt], b1v[nt], b1v[nt]};
        #pragma unroll
        for (int ks = 0; ks < 6; ++ks) {
            #pragma unroll
            for (int nt = 0; nt < 4; ++nt) {
                short8 bf = *(const short8*)&w1l[((ks * 4 + kg) * 64 + nt * 16 + c) * 8];
                acc[nt] = __builtin_amdgcn_mfma_f32_16x16x32_bf16(a[ks], bf, acc[nt], 0, 0, 0);
            }
        }
        #pragma unroll
        for (int nt = 0; nt < 4; ++nt) {
            #pragma unroll
            for (int i = 0; i < 4; ++i) {
                int rr = kg * 4 + i, cc = nt * 16 + c;
                hl[((cc >> 3) * 16 + rr) * 8 + (cc & 7)] = f2bf(fmaxf(acc[nt][i], 0.f));
            }
        }
        f32x4 acc2[4];
        #pragma unroll
        for (int nt = 0; nt < 4; ++nt) acc2[nt] = f32x4{b2v[nt], b2v[nt], b2v[nt], b2v[nt]};
        #pragma unroll
        for (int ks = 0; ks < 2; ++ks) {
            short8 ha = *(const short8*)&hl[((ks * 4 + kg) * 16 + c) * 8];
            #pragma unroll
            for (int nt = 0; nt < 4; ++nt)
                acc2[nt] = __builtin_amdgcn_mfma_f32_16x16x32_bf16(ha, w2f[ks][nt], acc2[nt], 0, 0, 0);
        }
        #pragma unroll
        for (int nt = 0; nt < 4; ++nt) {
            #pragma unroll
            for (int i = 0; i < 4; ++i) {
                int rr = kg * 4 + i, cc = nt * 16 + c;
                size_t off = (size_t)(e0 + rr) * 64 + cc;
                eb[off] = f2bf(bf2f(eb[off]) + 0.5f * acc2[nt][i]);
            }
        }
    }
}

// ======================= readout ===========================================
__global__ __launch_bounds__(256) void k_readout_mfma(
    const ushort* __restrict__ xb, const ushort* __restrict__ eb,
    const int* __restrict__ src, const int* __restrict__ dst,
    const ushort* __restrict__ w1s, const float* __restrict__ b1,
    const float* __restrict__ w2, const float* __restrict__ b2,
    const float* __restrict__ w3, const float* __restrict__ b3,
    float* __restrict__ logit)
{
    __shared__ ushort w1l[192 * 64];
    __shared__ ushort hw[4][64 * 50];
    int tid = threadIdx.x;
    #pragma unroll
    for (int i = 0; i < 6; ++i)
        *(short8*)&w1l[(i * 256 + tid) * 8] = *(const short8*)&w1s[(i * 256 + tid) * 8];
    __syncthreads();

    int wid = tid >> 6, lane = tid & 63;
    int c = lane & 15, kg = lane >> 4;
    float b1v[4];
    #pragma unroll
    for (int nt = 0; nt < 4; ++nt) b1v[nt] = (nt * 16 + c < 50) ? b1[nt * 16 + c] : 0.f;

    #pragma unroll 1
    for (int t4 = 0; t4 < 4; ++t4) {
        int e0 = blockIdx.x * 256 + wid * 64 + t4 * 16;
        int myedge = e0 + c;
        int s = src[myedge], d = dst[myedge];
        const ushort* xs = xb + (size_t)s * 64;
        const ushort* xd = xb + (size_t)d * 64;
        const ushort* ee = eb + (size_t)myedge * 64;
        short8 a[6];
        a[0] = brelu(*(const short8*)(xs + kg * 8));
        a[1] = brelu(*(const short8*)(xs + 32 + kg * 8));
        a[2] = brelu(*(const short8*)(xd + kg * 8));
        a[3] = brelu(*(const short8*)(xd + 32 + kg * 8));
        a[4] = *(const short8*)(ee + kg * 8);
        a[5] = *(const short8*)(ee + 32 + kg * 8);

        f32x4 acc[4];
        #pragma unroll
        for (int nt = 0; nt < 4; ++nt) acc[nt] = f32x4{b1v[nt], b1v[nt], b1v[nt], b1v[nt]};
        #pragma unroll
        for (int ks = 0; ks < 6; ++ks) {
            #pragma unroll
            for (int nt = 0; nt < 4; ++nt) {
                short8 bf = *(const short8*)&w1l[((ks * 4 + kg) * 64 + nt * 16 + c) * 8];
                acc[nt] = __builtin_amdgcn_mfma_f32_16x16x32_bf16(a[ks], bf, acc[nt], 0, 0, 0);
            }
        }
        #pragma unroll
        for (int nt = 0; nt < 4; ++nt) {
            #pragma unroll
            for (int i = 0; i < 4; ++i) {
                int rr = kg * 4 + i, cc = nt * 16 + c;
                if (cc < 50)
                    hw[wid][(t4 * 16 + rr) * 50 + cc] = f2bf(fmaxf(acc[nt][i], 0.f));
            }
        }
    }
    int edge = blockIdx.x * 256 + wid * 64 + lane;
    const ushort* hrow = &hw[wid][lane * 50];
    float a25[25];
    #pragma unroll
    for (int j = 0; j < 25; ++j) a25[j] = b2[j];
    #pragma unroll 2
    for (int k = 0; k < 50; ++k) {
        float hv = bf2f(hrow[k]);
        #pragma unroll
        for (int j = 0; j < 25; ++j) a25[j] = fmaf(hv, w2[k * 25 + j], a25[j]);
    }
    float lg = b3[0];
    #pragma unroll
    for (int k = 0; k < 25; ++k) lg = fmaf(fmaxf(a25[k], 0.f), w3[k], lg);
    logit[edge] = lg;
}

// ---------------------------------------------------------------------------
extern "C" void kernel_launch(void* const* d_in, const int* in_sizes, int n_in,
                              void* d_out, int out_size, void* d_ws, size_t ws_size,
                              hipStream_t stream)
{
    const float* x_in  = (const float*)d_in[0];
    const float* eattr = (const float*)d_in[1];
    const int*   src   = (const int*)d_in[2];
    const int*   dst   = (const int*)d_in[3];
    const float* n_w   = (const float*)d_in[4];
    const float* n_b   = (const float*)d_in[5];
    const float* e_w   = (const float*)d_in[6];
    const float* e_b   = (const float*)d_in[7];
    const float* lw    = (const float*)d_in[8];
    const float* lb    = (const float*)d_in[9];
    const float* cw1   = (const float*)d_in[10];
    const float* cb1   = (const float*)d_in[11];
    const float* cw2   = (const float*)d_in[12];
    const float* cb2   = (const float*)d_in[13];
    const float* ew1   = (const float*)d_in[14];
    const float* eb1   = (const float*)d_in[15];
    const float* ew2   = (const float*)d_in[16];
    const float* eb2   = (const float*)d_in[17];
    const float* gam   = (const float*)d_in[18];
    const float* bet   = (const float*)d_in[19];
    const float* m1w   = (const float*)d_in[20];
    const float* m1b   = (const float*)d_in[21];
    const float* m2w   = (const float*)d_in[22];
    const float* m2b   = (const float*)d_in[23];
    const float* m3w   = (const float*)d_in[24];
    const float* m3b   = (const float*)d_in[25];

    float* xbuf  = (float*)d_out;                  // [NN,64] f32 master (output 0)
    float* logit = xbuf + (size_t)NN * 64;         // [NE]

    // 16B-aligned buffers first, int buffers last
    ushort* eb     = (ushort*)d_ws;                   // [NE,64]
    float*  tmp    = (float*)(eb + (size_t)NE * 64);  // [NN,64] h
    float*  stats  = tmp + (size_t)NN * 64;           // 256
    ushort* w1s    = (ushort*)(stats + 256);          // 2*192*64
    ushort* w2s    = w1s + 2 * 192 * 64;              // 2*64*64
    ushort* m1s    = w2s + 2 * 64 * 64;               // 192*64
    ushort* xb     = m1s + 192 * 64;                  // [NN,64]
    ushort* wms    = xb + (size_t)NN * 64;            // 2*128*64
    ushort* cw1s   = wms + 2 * 128 * 64;              // 2*64*64
    ushort* cw2s   = cw1s + 2 * 64 * 64;              // 2*64*64
    ushort* nws    = cw2s + 2 * 64 * 64;              // 32*64
    ushort* ews    = nws + 32 * 64;                   // 32*64
    ushort* msgbuf = ews + 32 * 64;                   // [NE,64]
    int*    hist   = (int*)(msgbuf + (size_t)NE * 64);// NN
    int*    rp     = hist + NN;                       // NN+1
    int*    cursor = rp + NN + 1;                     // NN
    int*    parts  = cursor + NN;                     // 128
    int*    eidx   = parts + 128;                     // NE
    int*    ssrc   = eidx + NE;                       // NE

    // ---- CSR build (once; reused by both layers) ----
    hipMemsetAsync(hist, 0, NN * sizeof(int), stream);
    k_hist<<<NE / 256, 256, 0, stream>>>(dst, hist);
    k_scan_part<<<NB_SCAN, 256, 0, stream>>>(hist, rp, parts);
    k_scan_tops<<<1, 128, 0, stream>>>(parts, rp);
    k_scan_add<<<(NN + 255) / 256, 256, 0, stream>>>(rp, parts, cursor);
    k_scatter<<<NE / 256, 256, 0, stream>>>(src, dst, cursor, eidx, ssrc);

    // ---- weight prep ----
    k_w_subtile<<<48, 256, 0, stream>>>(ew1,            w1s,            192, 64);
    k_w_subtile<<<48, 256, 0, stream>>>(ew1 + 192 * 64, w1s + 192 * 64, 192, 64);
    k_w_subtile<<<16, 256, 0, stream>>>(ew2,            w2s,            64, 64);
    k_w_subtile<<<16, 256, 0, stream>>>(ew2 + 64 * 64,  w2s + 64 * 64,  64, 64);
    k_w_subtile<<<48, 256, 0, stream>>>(m1w,            m1s,            192, 50);
    k_w_msg<<<32, 256, 0, stream>>>(lw,           wms);
    k_w_msg<<<32, 256, 0, stream>>>(lw + 64 * 64, wms + 128 * 64);
    k_w_subtile<<<16, 256, 0, stream>>>(cw1,            cw1s,           64, 64);
    k_w_subtile<<<16, 256, 0, stream>>>(cw1 + 64 * 64,  cw1s + 64 * 64, 64, 64);
    k_w_subtile<<<16, 256, 0, stream>>>(cw2,            cw2s,           64, 64);
    k_w_subtile<<<16, 256, 0, stream>>>(cw2 + 64 * 64,  cw2s + 64 * 64, 64, 64);
    k_w_padk<<<8, 256, 0, stream>>>(n_w, nws, 32, 32);
    k_w_padk<<<8, 256, 0, stream>>>(e_w, ews, 16, 32);

    k_node_emb_mfma<<<(NN / 16 + 3) / 4, 256, 0, stream>>>(x_in, nws, n_b, xbuf, xb);
    k_edge_emb_mfma<<<NE / 64, 256, 0, stream>>>(eattr, ews, e_b, eb);

    for (int l = 0; l < 2; ++l) {
        hipMemsetAsync(stats, 0, 256 * sizeof(float), stream);
        k_msgA<<<NE / 256, 256, 0, stream>>>(xb, eb, eidx, ssrc,
                                             wms + l * 128 * 64, lb + l * 64, msgbuf);
        k_conv_csr<<<(NN / 16 + 3) / 4, 256, 0, stream>>>(
            xbuf, msgbuf, rp, tmp, cw1s + l * 64 * 64, cb1 + l * 64,
            cw2s + l * 64 * 64, cb2 + l * 64, stats);
        k_bnfin<<<1, 64, 0, stream>>>(stats, gam + l * 64, bet + l * 64);
        k_xupd4<<<NN * 16 / 256, 256, 0, stream>>>(xbuf, tmp, stats, xb);
        k_emlp_mfma<<<NE / 256, 256, 0, stream>>>(xb, eb, src, dst,
                                                  w1s + l * 192 * 64, eb1 + l * 64,
                                                  w2s + l * 64 * 64, eb2 + l * 64);
    }

    k_readout_mfma<<<NE / 256, 256, 0, stream>>>(xb, eb, src, dst,
                                                 m1s, m1b, m2w, m2b, m3w, m3b, logit);
}